// Round 9
// baseline (1663.595 us; speedup 1.0000x reference)
//
#include <hip/hip_runtime.h>
#include <math.h>

#define N_NODES 883
#define KPAD 896
#define T_STEPS 12
#define DE 10
#define KI 132          // CHEB_K * (DIN + DOUT) = 2 * 66
#define NCOLS 8192      // 2 dirs * 64 batch * 64 hidden
#define XCOLS 1536      // T * B * DIN
#define WSTR 160        // weight row stride (k padded 132 -> 160; k=132 = bias col)
#define ASTR 168        // LDS inp row stride (fp16 elems)
#define GOSTR (128 * WSTR)   // 20480 gate weight elems per (n,dir)
#define COSTR (64 * WSTR)    // 10240 cand weight elems per (n,dir)

typedef _Float16 f16;
typedef __attribute__((ext_vector_type(2))) _Float16 f16x2;
typedef __attribute__((ext_vector_type(4))) _Float16 f16x4;
typedef __attribute__((ext_vector_type(8))) _Float16 f16x8;
typedef __attribute__((ext_vector_type(4))) float f32x4;

__device__ inline void gload16(const void* g, void* l) {
    __builtin_amdgcn_global_load_lds(
        (const __attribute__((address_space(1))) unsigned int*)g,
        (__attribute__((address_space(3))) unsigned int*)l, 16, 0, 0);
}

// ---------------------------------------------------------------------------
// Sh[n][m] (fp16, padded to 896x896) = softmax(relu(E E^T), axis=1) + adj
// ---------------------------------------------------------------------------
__global__ __launch_bounds__(256) void k_computeS(const float* __restrict__ E,
                                                  const float* __restrict__ adj,
                                                  f16* __restrict__ Sh) {
    int n = blockIdx.x;
    int tid = threadIdx.x;
    __shared__ float l[N_NODES];
    __shared__ float red[8];
    float En[DE];
#pragma unroll
    for (int d = 0; d < DE; ++d) En[d] = E[n * DE + d];

    float lmax = -1e30f;
    for (int m = tid; m < N_NODES; m += 256) {
        float dot = 0.f;
#pragma unroll
        for (int d = 0; d < DE; ++d) dot += En[d] * E[m * DE + d];
        dot = fmaxf(dot, 0.f);
        l[m] = dot;
        lmax = fmaxf(lmax, dot);
    }
    int wave = tid >> 6, lane = tid & 63;
    for (int off = 32; off > 0; off >>= 1) lmax = fmaxf(lmax, __shfl_down(lmax, off));
    if (lane == 0) red[wave] = lmax;
    __syncthreads();
    float gmax = fmaxf(fmaxf(red[0], red[1]), fmaxf(red[2], red[3]));
    __syncthreads();

    float lsum = 0.f;
    for (int m = tid; m < N_NODES; m += 256) {
        float e = expf(l[m] - gmax);
        l[m] = e;
        lsum += e;
    }
    for (int off = 32; off > 0; off >>= 1) lsum += __shfl_down(lsum, off);
    if (lane == 0) red[wave] = lsum;
    __syncthreads();
    float inv = 1.0f / (red[0] + red[1] + red[2] + red[3]);
    for (int m = tid; m < N_NODES; m += 256) {
        Sh[(size_t)n * KPAD + m] = (f16)(l[m] * inv + adj[(size_t)n * N_NODES + m]);
    }
}

// ---------------------------------------------------------------------------
// XTt[c][m] (fp16, [1536][896]) = x[b,t,m,i] with c=(t*64+b)*2+i
// ---------------------------------------------------------------------------
__global__ void k_buildXT(const float* __restrict__ x, f16* __restrict__ XTt) {
    int idx = blockIdx.x * blockDim.x + threadIdx.x;
    if (idx >= XCOLS * N_NODES) return;
    int m = idx % N_NODES;
    int c = idx / N_NODES;
    int t = c >> 7;
    int b = (c >> 1) & 63;
    int i = c & 1;
    XTt[(size_t)c * KPAD + m] = (f16)x[(((size_t)b * T_STEPS + t) * N_NODES + m) * 2 + i];
}

// ---------------------------------------------------------------------------
// Repack pooled weights into output flat order; k==KI carries the pooled BIAS
// (the applies feed inp[k=132]=1.0 so bias rides through the MFMA).
// ---------------------------------------------------------------------------
__global__ void k_reorgW(const float* __restrict__ Wg_f, const float* __restrict__ Wg_b,
                         const float* __restrict__ Wc_f, const float* __restrict__ Wc_b,
                         const float* __restrict__ bg_f, const float* __restrict__ bg_b,
                         const float* __restrict__ bc_f, const float* __restrict__ bc_b,
                         float* __restrict__ Wg_r, float* __restrict__ Wc_r) {
    const int GTOT = 2 * DE * GOSTR;   // 409600
    const int CTOT = 2 * DE * COSTR;   // 204800
    int idx = blockIdx.x * blockDim.x + threadIdx.x;
    if (idx < GTOT) {
        int k = idx % WSTR;
        int o = (idx / WSTR) & 127;
        int d = (idx / GOSTR) % DE;
        int dir = idx / (DE * GOSTR);
        float v = 0.f;
        if (k < KI) {
            const float* W = dir ? Wg_b : Wg_f;
            int kc = k / 66, i = k % 66;
            v = W[(((size_t)d * 2 + kc) * 66 + i) * 128 + o];
        } else if (k == KI) {
            v = (dir ? bg_b : bg_f)[d * 128 + o];
        }
        Wg_r[idx] = v;
    } else if (idx < GTOT + CTOT) {
        int j = idx - GTOT;
        int k = j % WSTR;
        int o = (j / WSTR) & 63;
        int d = (j / COSTR) % DE;
        int dir = j / (DE * COSTR);
        float v = 0.f;
        if (k < KI) {
            const float* W = dir ? Wc_b : Wc_f;
            int kc = k / 66, i = k % 66;
            v = W[(((size_t)d * 2 + kc) * 66 + i) * 64 + o];
        } else if (k == KI) {
            v = (dir ? bc_b : bc_f)[d * 64 + o];
        }
        Wc_r[j] = v;
    }
}

// ---------------------------------------------------------------------------
// Per-node weights from repacked pools. Block = (16-node group, dir, f-slice).
// ---------------------------------------------------------------------------
__global__ __launch_bounds__(256) void k_buildW2(
    const float* __restrict__ E,
    const float* __restrict__ Wg_r, const float* __restrict__ Wc_r,
    f16* __restrict__ WgT, f16* __restrict__ WcT) {
    int grp = blockIdx.x, dir = blockIdx.y, z = blockIdx.z;
    int n0 = grp * 16;
    int tid = threadIdx.x;
    __shared__ float Es[16][DE];
    if (tid < 16 * DE) {
        int nn = tid / DE, d = tid % DE;
        int n = n0 + nn;
        Es[nn][d] = (n < N_NODES) ? E[n * DE + d] : 0.f;
    }
    __syncthreads();

    bool gate = z < 4;
    const float* src = gate ? (Wg_r + (size_t)dir * DE * GOSTR)
                            : (Wc_r + (size_t)dir * DE * COSTR);
    f16* dst = gate ? WgT : WcT;
    int ostr = gate ? GOSTR : COSTR;
    int slot0 = gate ? z * 1280 : (z - 4) * 1280;

#pragma unroll
    for (int it = 0; it < 5; ++it) {
        int f = (slot0 + it * 256 + tid) * 4;
        float4 v[DE];
#pragma unroll
        for (int d = 0; d < DE; ++d)
            v[d] = *(const float4*)&src[(size_t)d * ostr + f];
#pragma unroll
        for (int nn = 0; nn < 16; ++nn) {
            int n = n0 + nn;
            if (n >= N_NODES) break;
            float a0 = 0.f, a1 = 0.f, a2 = 0.f, a3 = 0.f;
#pragma unroll
            for (int d = 0; d < DE; ++d) {
                float e = Es[nn][d];
                a0 += e * v[d].x; a1 += e * v[d].y;
                a2 += e * v[d].z; a3 += e * v[d].w;
            }
            f16x4 r = {(f16)a0, (f16)a1, (f16)a2, (f16)a3};
            *(f16x4*)&dst[(size_t)(dir * N_NODES + n) * ostr + f] = r;
        }
    }
}

// ---------------------------------------------------------------------------
// VT[c][n'] (f16 [NCOLS][KPAD]) = V[n][c] (f16 [N_NODES][NCOLS]); zero-pads n'.
// ---------------------------------------------------------------------------
__global__ __launch_bounds__(256) void k_transpose(const f16* __restrict__ V,
                                                   f16* __restrict__ VT) {
    __shared__ f16 tile[64][66];
    int c0 = blockIdx.x * 64;
    int n0 = blockIdx.y * 64;
    int tid = threadIdx.x;
#pragma unroll
    for (int it = 0; it < 2; ++it) {
        int chunk = tid + it * 256;
        int r = chunk >> 3, g = chunk & 7;
        int n = n0 + r;
        f16 tmp[8];
        if (n < N_NODES) {
            f16x8 v = *(const f16x8*)&V[(size_t)n * NCOLS + c0 + g * 8];
#pragma unroll
            for (int j = 0; j < 8; ++j) tmp[j] = v[j];
        } else {
#pragma unroll
            for (int j = 0; j < 8; ++j) tmp[j] = (f16)0.f;
        }
#pragma unroll
        for (int j = 0; j < 8; ++j) tile[g * 8 + j][r] = tmp[j];
    }
    __syncthreads();
#pragma unroll
    for (int it = 0; it < 2; ++it) {
        int chunk = tid + it * 256;
        int cc = chunk >> 3, m = chunk & 7;
        f16x8 v;
#pragma unroll
        for (int j = 0; j < 8; ++j) v[j] = tile[cc][m * 8 + j];
        *(f16x8*)&VT[(size_t)(c0 + cc) * KPAD + n0 + m * 8] = v;
    }
}

// ---------------------------------------------------------------------------
// C[r][c] (fp16) = sum_k A[r][k] * Bt[c][k]. Double-buffered 2-phase K-loop
// (T3 minimal recipe): issue next tile's global_load_lds into the alternate
// buffer BEFORE computing the current one; the single __syncthreads per iter
// (built-in vmcnt/lgkmcnt drain) lands AFTER compute, so HBM latency hides
// under ds_read+MFMA. Matters here: 448 blocks => <2 blocks/CU, no implicit
// inter-block overlap to hide the old stage->sync->compute serialization.
// ---------------------------------------------------------------------------
__global__ __launch_bounds__(256) void k_gemm_f16(const f16* __restrict__ A,
                                                  const f16* __restrict__ Bt,
                                                  f16* __restrict__ C, int NC) {
    __shared__ f16 Als[2][128 * 32];
    __shared__ f16 Bls[2][128 * 32];
    int tid = threadIdx.x;
    int w = tid >> 6, l = tid & 63;
    int wr = w >> 1, wc = w & 1;
    int row0 = blockIdx.y * 128;
    int col0 = blockIdx.x * 128;
    int rr = l >> 2;
    int cc = (l & 3) * 8;
    int lr = l & 15, lg = l >> 4;

    const f16* a0 = A + (size_t)(row0 + w * 32 + rr) * KPAD + cc;
    const f16* a1 = a0 + (size_t)16 * KPAD;
    const f16* b0 = Bt + (size_t)(col0 + w * 32 + rr) * KPAD + cc;
    const f16* b1 = b0 + (size_t)16 * KPAD;
    const int lo = (w * 32) * 32;          // this wave's staging slot (elems)

    f32x4 acc[4][4];
#pragma unroll
    for (int m = 0; m < 4; ++m)
#pragma unroll
        for (int n = 0; n < 4; ++n) acc[m][n] = (f32x4)(0.f);

    const int nk = KPAD / 32;
    // prologue: stage tile 0 into buffer 0
    gload16(a0, &Als[0][lo]);
    gload16(a1, &Als[0][lo + 16 * 32]);
    gload16(b0, &Bls[0][lo]);
    gload16(b1, &Bls[0][lo + 16 * 32]);
    __syncthreads();

    int cur = 0;
    for (int kt = 0; kt < nk; ++kt) {
        if (kt + 1 < nk) {                  // issue next-tile loads (async)
            int k0 = (kt + 1) * 32;
            int nx = cur ^ 1;
            gload16(a0 + k0, &Als[nx][lo]);
            gload16(a1 + k0, &Als[nx][lo + 16 * 32]);
            gload16(b0 + k0, &Bls[nx][lo]);
            gload16(b1 + k0, &Bls[nx][lo + 16 * 32]);
        }
        f16x8 af[4], bf[4];
#pragma unroll
        for (int m = 0; m < 4; ++m)
            af[m] = *(const f16x8*)&Als[cur][(wr * 64 + m * 16 + lr) * 32 + lg * 8];
#pragma unroll
        for (int n = 0; n < 4; ++n)
            bf[n] = *(const f16x8*)&Bls[cur][(wc * 64 + n * 16 + lr) * 32 + lg * 8];
#pragma unroll
        for (int m = 0; m < 4; ++m)
#pragma unroll
            for (int n = 0; n < 4; ++n)
                acc[m][n] = __builtin_amdgcn_mfma_f32_16x16x32_f16(af[m], bf[n], acc[m][n], 0, 0, 0);
        __syncthreads();                    // drains prefetch; next buf ready
        cur ^= 1;
    }

#pragma unroll
    for (int m = 0; m < 4; ++m) {
        int gr0 = row0 + wr * 64 + m * 16 + lg * 4;
#pragma unroll
        for (int n = 0; n < 4; ++n) {
            int gc = col0 + wc * 64 + n * 16 + lr;
            f32x4 v = acc[m][n];
#pragma unroll
            for (int q = 0; q < 4; ++q) {
                int r = gr0 + q;
                if (r < N_NODES) C[(size_t)r * NC + gc] = (f16)v[q];
            }
        }
    }
}

// ---------------------------------------------------------------------------
// Gate apply (MFMA): per (n,dir), C[64 b][128 o] = inp[64][160] x WgT[n][128][160]
// ---------------------------------------------------------------------------
__global__ __launch_bounds__(256) void k_apply_gate(
    const float* __restrict__ x, const f16* __restrict__ Hh,
    const f16* __restrict__ SXh, const f16* __restrict__ SHh,
    const f16* __restrict__ WgT,
    f16* __restrict__ Zh, f16* __restrict__ RHh, int t, int first) {
    int n = blockIdx.x, dir = blockIdx.y;
    int tid = threadIdx.x;
    int tt = dir ? (T_STEPS - 1 - t) : t;
    __shared__ f16 inpA[64 * ASTR];

    const f16* hhrow = Hh + (size_t)n * NCOLS + dir * 4096;
    const f16* shrow = SHh + (size_t)n * NCOLS + dir * 4096;

#pragma unroll
    for (int it = 0; it < 8; ++it) {
        int i2 = tid + it * 256;
        int b = i2 >> 5, jp = i2 & 31;
        *(unsigned*)&inpA[b * ASTR + 2 + 2 * jp] = *(const unsigned*)&hhrow[b * 64 + 2 * jp];
        *(unsigned*)&inpA[b * ASTR + 68 + 2 * jp] =
            first ? 0u : *(const unsigned*)&shrow[b * 64 + 2 * jp];
    }
    if (tid < 128) {
        int b = tid >> 1, i = tid & 1;
        inpA[b * ASTR + i] = (f16)x[(((size_t)b * T_STEPS + tt) * N_NODES + n) * 2 + i];
        inpA[b * ASTR + 66 + i] = SXh[(size_t)n * XCOLS + tt * 128 + b * 2 + i];
    }
    for (int idx = tid; idx < 64 * 14; idx += 256) {
        int b = idx / 14, p = idx % 14;
        *(unsigned*)&inpA[b * ASTR + 132 + 2 * p] = (p == 0) ? 0x00003C00u : 0u;
    }
    __syncthreads();

    int w = tid >> 6, l = tid & 63;
    int lr = l & 15, lg = l >> 4;
    int o0 = w * 32;
    const f16* wbase = WgT + (size_t)(dir * N_NODES + n) * GOSTR;

    f32x4 acc[4][2];
#pragma unroll
    for (int m = 0; m < 4; ++m)
#pragma unroll
        for (int j = 0; j < 2; ++j) acc[m][j] = (f32x4)(0.f);

#pragma unroll
    for (int kt = 0; kt < 5; ++kt) {
        int k0 = kt * 32 + lg * 8;
        f16x8 af[4], bf[2];
#pragma unroll
        for (int m = 0; m < 4; ++m)
            af[m] = *(const f16x8*)&inpA[(m * 16 + lr) * ASTR + k0];
#pragma unroll
        for (int j = 0; j < 2; ++j)
            bf[j] = *(const f16x8*)&wbase[(size_t)(o0 + j * 16 + lr) * WSTR + k0];
#pragma unroll
        for (int m = 0; m < 4; ++m)
#pragma unroll
            for (int j = 0; j < 2; ++j)
                acc[m][j] = __builtin_amdgcn_mfma_f32_16x16x32_f16(af[m], bf[j], acc[m][j], 0, 0, 0);
    }

    f16* zrow = Zh + (size_t)(dir * N_NODES + n) * 4096;
    f16* rhrow = RHh + (size_t)n * NCOLS + dir * 4096;
#pragma unroll
    for (int j = 0; j < 2; ++j) {
        int o = o0 + j * 16 + lr;
        if (o < 64) {
#pragma unroll
            for (int m = 0; m < 4; ++m) {
                int b0 = m * 16 + lg * 4;
                f32x4 v = acc[m][j];
#pragma unroll
                for (int q = 0; q < 4; ++q)
                    zrow[(b0 + q) * 64 + o] = (f16)(1.f / (1.f + expf(-v[q])));
            }
        } else {
            int jj = o - 64;
#pragma unroll
            for (int m = 0; m < 4; ++m) {
                int b0 = m * 16 + lg * 4;
                f32x4 v = acc[m][j];
#pragma unroll
                for (int q = 0; q < 4; ++q) {
                    float r = 1.f / (1.f + expf(-v[q]));
                    rhrow[(b0 + q) * 64 + jj] =
                        (f16)(r * (float)hhrow[(b0 + q) * 64 + jj]);
                }
            }
        }
    }
}

// ---------------------------------------------------------------------------
// Candidate apply (MFMA): per (n,dir), C[64 b][64 o]. fp16 state update.
// ---------------------------------------------------------------------------
__global__ __launch_bounds__(256) void k_apply_cand(
    const float* __restrict__ x, const f16* __restrict__ SXh,
    const f16* __restrict__ SRHh, const f16* __restrict__ RHh,
    const f16* __restrict__ WcT, const f16* __restrict__ Zh,
    f16* __restrict__ Hh, float* __restrict__ out, int t) {
    int n = blockIdx.x, dir = blockIdx.y;
    int tid = threadIdx.x;
    int tt = dir ? (T_STEPS - 1 - t) : t;
    __shared__ f16 inpA[64 * ASTR];

    const f16* rhrow = RHh + (size_t)n * NCOLS + dir * 4096;
    const f16* srhrow = SRHh + (size_t)n * NCOLS + dir * 4096;

#pragma unroll
    for (int it = 0; it < 8; ++it) {
        int i2 = tid + it * 256;
        int b = i2 >> 5, jp = i2 & 31;
        *(unsigned*)&inpA[b * ASTR + 2 + 2 * jp] = *(const unsigned*)&rhrow[b * 64 + 2 * jp];
        *(unsigned*)&inpA[b * ASTR + 68 + 2 * jp] = *(const unsigned*)&srhrow[b * 64 + 2 * jp];
    }
    if (tid < 128) {
        int b = tid >> 1, i = tid & 1;
        inpA[b * ASTR + i] = (f16)x[(((size_t)b * T_STEPS + tt) * N_NODES + n) * 2 + i];
        inpA[b * ASTR + 66 + i] = SXh[(size_t)n * XCOLS + tt * 128 + b * 2 + i];
    }
    for (int idx = tid; idx < 64 * 14; idx += 256) {
        int b = idx / 14, p = idx % 14;
        *(unsigned*)&inpA[b * ASTR + 132 + 2 * p] = (p == 0) ? 0x00003C00u : 0u;
    }
    __syncthreads();

    int w = tid >> 6, l = tid & 63;
    int lr = l & 15, lg = l >> 4;
    const f16* wbase = WcT + (size_t)(dir * N_NODES + n) * COSTR;

    f32x4 acc[4];
#pragma unroll
    for (int j = 0; j < 4; ++j) acc[j] = (f32x4)(0.f);

#pragma unroll
    for (int kt = 0; kt < 5; ++kt) {
        int k0 = kt * 32 + lg * 8;
        f16x8 af = *(const f16x8*)&inpA[(w * 16 + lr) * ASTR + k0];
        f16x8 bf[4];
#pragma unroll
        for (int j = 0; j < 4; ++j)
            bf[j] = *(const f16x8*)&wbase[(size_t)(j * 16 + lr) * WSTR + k0];
#pragma unroll
        for (int j = 0; j < 4; ++j)
            acc[j] = __builtin_amdgcn_mfma_f32_16x16x32_f16(af, bf[j], acc[j], 0, 0, 0);
    }

    const f16* zrow = Zh + (size_t)(dir * N_NODES + n) * 4096;
    f16* hhrow = Hh + (size_t)n * NCOLS + dir * 4096;
#pragma unroll
    for (int j = 0; j < 4; ++j) {
        int o = j * 16 + lr;
        f32x4 v = acc[j];
#pragma unroll
        for (int q = 0; q < 4; ++q) {
            int b = w * 16 + lg * 4 + q;
            float hc = tanhf(v[q]);
            float zv = (float)zrow[b * 64 + o];
            float hp = (float)hhrow[b * 64 + o];
            float hn = zv * hp + (1.f - zv) * hc;
            hhrow[b * 64 + o] = (f16)hn;
            out[(((size_t)b * T_STEPS + t) * N_NODES + n) * 128 + dir * 64 + o] = hn;
        }
    }
}

// ---------------------------------------------------------------------------
extern "C" void kernel_launch(void* const* d_in, const int* in_sizes, int n_in,
                              void* d_out, int out_size, void* d_ws, size_t ws_size,
                              hipStream_t stream) {
    const float* x    = (const float*)d_in[0];
    const float* adj  = (const float*)d_in[1];
    const float* E    = (const float*)d_in[2];
    const float* Wg_f = (const float*)d_in[3];
    const float* bg_f = (const float*)d_in[4];
    const float* Wc_f = (const float*)d_in[5];
    const float* bc_f = (const float*)d_in[6];
    const float* Wg_b = (const float*)d_in[7];
    const float* bg_b = (const float*)d_in[8];
    const float* Wc_b = (const float*)d_in[9];
    const float* bc_b = (const float*)d_in[10];
    float* out = (float*)d_out;

    size_t off = 0;
    auto alloc = [&](size_t bytes) {
        void* p = (char*)d_ws + off;
        off += (bytes + 255) & ~(size_t)255;
        return p;
    };
    f16*   Sh   = (f16*)alloc((size_t)KPAD * KPAD * 2);
    f16*   XTt  = (f16*)alloc((size_t)XCOLS * KPAD * 2);
    f16*   SXh  = (f16*)alloc((size_t)N_NODES * XCOLS * 2);
    f16*   Hh   = (f16*)alloc((size_t)N_NODES * NCOLS * 2);
    f16*   SHh  = (f16*)alloc((size_t)N_NODES * NCOLS * 2);
    f16*   RHh  = (f16*)alloc((size_t)N_NODES * NCOLS * 2);
    f16*   Zh   = (f16*)alloc((size_t)N_NODES * NCOLS * 2);
    f16*   HBt  = (f16*)alloc((size_t)NCOLS * KPAD * 2);
    f16*   RHBt = (f16*)alloc((size_t)NCOLS * KPAD * 2);
    f16*   WgT  = (f16*)alloc((size_t)2 * N_NODES * GOSTR * 2);
    f16*   WcT  = (f16*)alloc((size_t)2 * N_NODES * COSTR * 2);
    // Overlay: Wg_r/Wc_r (2.46 MB, consumed by k_buildW2 before the time loop)
    // live inside RHBt (14.68 MB), first written at t=0's transpose, after
    // buildW2. Keeps workspace within the replay-proven footprint (r6 lesson).
    float* Wg_r = (float*)RHBt;
    float* Wc_r = Wg_r + (size_t)2 * DE * GOSTR;

    hipMemsetAsync(Sh, 0, (size_t)KPAD * KPAD * 2, stream);
    hipMemsetAsync(XTt, 0, (size_t)XCOLS * KPAD * 2, stream);
    hipMemsetAsync(Hh, 0, (size_t)N_NODES * NCOLS * 2, stream);

    k_computeS<<<N_NODES, 256, 0, stream>>>(E, adj, Sh);
    {
        int total = XCOLS * N_NODES;
        k_buildXT<<<(total + 255) / 256, 256, 0, stream>>>(x, XTt);
    }
    {
        int total = 2 * DE * (GOSTR + COSTR);
        k_reorgW<<<(total + 255) / 256, 256, 0, stream>>>(Wg_f, Wg_b, Wc_f, Wc_b,
                                                          bg_f, bg_b, bc_f, bc_b,
                                                          Wg_r, Wc_r);
    }
    k_buildW2<<<dim3(56, 2, 6), 256, 0, stream>>>(E, Wg_r, Wc_r, WgT, WcT);
    k_gemm_f16<<<dim3(XCOLS / 128, 7), 256, 0, stream>>>(Sh, XTt, SXh, XCOLS);

    dim3 gnode(N_NODES, 2);
    dim3 gmain(NCOLS / 128, 7);
    dim3 gtr(NCOLS / 64, KPAD / 64);
    for (int t = 0; t < T_STEPS; ++t) {
        if (t > 0)
            k_gemm_f16<<<gmain, 256, 0, stream>>>(Sh, HBt, SHh, NCOLS);
        k_apply_gate<<<gnode, 256, 0, stream>>>(x, Hh, SXh, SHh, WgT,
                                                Zh, RHh, t, t == 0 ? 1 : 0);
        k_transpose<<<gtr, 256, 0, stream>>>(RHh, RHBt);
        k_gemm_f16<<<gmain, 256, 0, stream>>>(Sh, RHBt, SHh, NCOLS);
        k_apply_cand<<<gnode, 256, 0, stream>>>(x, SXh, SHh, RHh, WcT,
                                                Zh, Hh, out, t);
        k_transpose<<<gtr, 256, 0, stream>>>(Hh, HBt);
    }
}

// Round 10
// 1573.806 us; speedup vs baseline: 1.0571x; 1.0571x over previous
//
#include <hip/hip_runtime.h>
#include <math.h>

#define N_NODES 883
#define KPAD 896
#define T_STEPS 12
#define DE 10
#define KI 132          // CHEB_K * (DIN + DOUT) = 2 * 66
#define NCOLS 8192      // 2 dirs * 64 batch * 64 hidden
#define XCOLS 1536      // T * B * DIN
#define WSTR 160        // weight row stride (k padded 132 -> 160; k=132 = bias col)
#define ASTR 168        // LDS inp row stride (fp16 elems)
#define GOSTR (128 * WSTR)   // 20480 gate weight elems per (n,dir)
#define COSTR (64 * WSTR)    // 10240 cand weight elems per (n,dir)

typedef _Float16 f16;
typedef __attribute__((ext_vector_type(2))) _Float16 f16x2;
typedef __attribute__((ext_vector_type(4))) _Float16 f16x4;
typedef __attribute__((ext_vector_type(8))) _Float16 f16x8;
typedef __attribute__((ext_vector_type(4))) float f32x4;

__device__ inline void gload16(const void* g, void* l) {
    __builtin_amdgcn_global_load_lds(
        (const __attribute__((address_space(1))) unsigned int*)g,
        (__attribute__((address_space(3))) unsigned int*)l, 16, 0, 0);
}

// ---------------------------------------------------------------------------
// Sh[n][m] (fp16, padded to 896x896) = softmax(relu(E E^T), axis=1) + adj
// ---------------------------------------------------------------------------
__global__ __launch_bounds__(256) void k_computeS(const float* __restrict__ E,
                                                  const float* __restrict__ adj,
                                                  f16* __restrict__ Sh) {
    int n = blockIdx.x;
    int tid = threadIdx.x;
    __shared__ float l[N_NODES];
    __shared__ float red[8];
    float En[DE];
#pragma unroll
    for (int d = 0; d < DE; ++d) En[d] = E[n * DE + d];

    float lmax = -1e30f;
    for (int m = tid; m < N_NODES; m += 256) {
        float dot = 0.f;
#pragma unroll
        for (int d = 0; d < DE; ++d) dot += En[d] * E[m * DE + d];
        dot = fmaxf(dot, 0.f);
        l[m] = dot;
        lmax = fmaxf(lmax, dot);
    }
    int wave = tid >> 6, lane = tid & 63;
    for (int off = 32; off > 0; off >>= 1) lmax = fmaxf(lmax, __shfl_down(lmax, off));
    if (lane == 0) red[wave] = lmax;
    __syncthreads();
    float gmax = fmaxf(fmaxf(red[0], red[1]), fmaxf(red[2], red[3]));
    __syncthreads();

    float lsum = 0.f;
    for (int m = tid; m < N_NODES; m += 256) {
        float e = expf(l[m] - gmax);
        l[m] = e;
        lsum += e;
    }
    for (int off = 32; off > 0; off >>= 1) lsum += __shfl_down(lsum, off);
    if (lane == 0) red[wave] = lsum;
    __syncthreads();
    float inv = 1.0f / (red[0] + red[1] + red[2] + red[3]);
    for (int m = tid; m < N_NODES; m += 256) {
        Sh[(size_t)n * KPAD + m] = (f16)(l[m] * inv + adj[(size_t)n * N_NODES + m]);
    }
}

// ---------------------------------------------------------------------------
// XTt[c][m] (fp16, [1536][896]) = x[b,t,m,i] with c=(t*64+b)*2+i
// ---------------------------------------------------------------------------
__global__ void k_buildXT(const float* __restrict__ x, f16* __restrict__ XTt) {
    int idx = blockIdx.x * blockDim.x + threadIdx.x;
    if (idx >= XCOLS * N_NODES) return;
    int m = idx % N_NODES;
    int c = idx / N_NODES;
    int t = c >> 7;
    int b = (c >> 1) & 63;
    int i = c & 1;
    XTt[(size_t)c * KPAD + m] = (f16)x[(((size_t)b * T_STEPS + t) * N_NODES + m) * 2 + i];
}

// ---------------------------------------------------------------------------
// Repack pooled weights into output flat order; k==KI carries the pooled BIAS
// (the applies feed inp[k=132]=1.0 so bias rides through the MFMA).
// ---------------------------------------------------------------------------
__global__ void k_reorgW(const float* __restrict__ Wg_f, const float* __restrict__ Wg_b,
                         const float* __restrict__ Wc_f, const float* __restrict__ Wc_b,
                         const float* __restrict__ bg_f, const float* __restrict__ bg_b,
                         const float* __restrict__ bc_f, const float* __restrict__ bc_b,
                         float* __restrict__ Wg_r, float* __restrict__ Wc_r) {
    const int GTOT = 2 * DE * GOSTR;   // 409600
    const int CTOT = 2 * DE * COSTR;   // 204800
    int idx = blockIdx.x * blockDim.x + threadIdx.x;
    if (idx < GTOT) {
        int k = idx % WSTR;
        int o = (idx / WSTR) & 127;
        int d = (idx / GOSTR) % DE;
        int dir = idx / (DE * GOSTR);
        float v = 0.f;
        if (k < KI) {
            const float* W = dir ? Wg_b : Wg_f;
            int kc = k / 66, i = k % 66;
            v = W[(((size_t)d * 2 + kc) * 66 + i) * 128 + o];
        } else if (k == KI) {
            v = (dir ? bg_b : bg_f)[d * 128 + o];
        }
        Wg_r[idx] = v;
    } else if (idx < GTOT + CTOT) {
        int j = idx - GTOT;
        int k = j % WSTR;
        int o = (j / WSTR) & 63;
        int d = (j / COSTR) % DE;
        int dir = j / (DE * COSTR);
        float v = 0.f;
        if (k < KI) {
            const float* W = dir ? Wc_b : Wc_f;
            int kc = k / 66, i = k % 66;
            v = W[(((size_t)d * 2 + kc) * 66 + i) * 64 + o];
        } else if (k == KI) {
            v = (dir ? bc_b : bc_f)[d * 64 + o];
        }
        Wc_r[j] = v;
    }
}

// ---------------------------------------------------------------------------
// Per-node weights from repacked pools. Block = (16-node group, dir, f-slice).
// ---------------------------------------------------------------------------
__global__ __launch_bounds__(256) void k_buildW2(
    const float* __restrict__ E,
    const float* __restrict__ Wg_r, const float* __restrict__ Wc_r,
    f16* __restrict__ WgT, f16* __restrict__ WcT) {
    int grp = blockIdx.x, dir = blockIdx.y, z = blockIdx.z;
    int n0 = grp * 16;
    int tid = threadIdx.x;
    __shared__ float Es[16][DE];
    if (tid < 16 * DE) {
        int nn = tid / DE, d = tid % DE;
        int n = n0 + nn;
        Es[nn][d] = (n < N_NODES) ? E[n * DE + d] : 0.f;
    }
    __syncthreads();

    bool gate = z < 4;
    const float* src = gate ? (Wg_r + (size_t)dir * DE * GOSTR)
                            : (Wc_r + (size_t)dir * DE * COSTR);
    f16* dst = gate ? WgT : WcT;
    int ostr = gate ? GOSTR : COSTR;
    int slot0 = gate ? z * 1280 : (z - 4) * 1280;

#pragma unroll
    for (int it = 0; it < 5; ++it) {
        int f = (slot0 + it * 256 + tid) * 4;
        float4 v[DE];
#pragma unroll
        for (int d = 0; d < DE; ++d)
            v[d] = *(const float4*)&src[(size_t)d * ostr + f];
#pragma unroll
        for (int nn = 0; nn < 16; ++nn) {
            int n = n0 + nn;
            if (n >= N_NODES) break;
            float a0 = 0.f, a1 = 0.f, a2 = 0.f, a3 = 0.f;
#pragma unroll
            for (int d = 0; d < DE; ++d) {
                float e = Es[nn][d];
                a0 += e * v[d].x; a1 += e * v[d].y;
                a2 += e * v[d].z; a3 += e * v[d].w;
            }
            f16x4 r = {(f16)a0, (f16)a1, (f16)a2, (f16)a3};
            *(f16x4*)&dst[(size_t)(dir * N_NODES + n) * ostr + f] = r;
        }
    }
}

// ---------------------------------------------------------------------------
// VT[c][n'] (f16 [NCOLS][KPAD]) = V[n][c] (f16 [N_NODES][NCOLS]); zero-pads n'.
// ---------------------------------------------------------------------------
__global__ __launch_bounds__(256) void k_transpose(const f16* __restrict__ V,
                                                   f16* __restrict__ VT) {
    __shared__ f16 tile[64][66];
    int c0 = blockIdx.x * 64;
    int n0 = blockIdx.y * 64;
    int tid = threadIdx.x;
#pragma unroll
    for (int it = 0; it < 2; ++it) {
        int chunk = tid + it * 256;
        int r = chunk >> 3, g = chunk & 7;
        int n = n0 + r;
        f16 tmp[8];
        if (n < N_NODES) {
            f16x8 v = *(const f16x8*)&V[(size_t)n * NCOLS + c0 + g * 8];
#pragma unroll
            for (int j = 0; j < 8; ++j) tmp[j] = v[j];
        } else {
#pragma unroll
            for (int j = 0; j < 8; ++j) tmp[j] = (f16)0.f;
        }
#pragma unroll
        for (int j = 0; j < 8; ++j) tile[g * 8 + j][r] = tmp[j];
    }
    __syncthreads();
#pragma unroll
    for (int it = 0; it < 2; ++it) {
        int chunk = tid + it * 256;
        int cc = chunk >> 3, m = chunk & 7;
        f16x8 v;
#pragma unroll
        for (int j = 0; j < 8; ++j) v[j] = tile[cc][m * 8 + j];
        *(f16x8*)&VT[(size_t)(c0 + cc) * KPAD + n0 + m * 8] = v;
    }
}

// ---------------------------------------------------------------------------
// C[r][c] (fp16) = sum_k A[r][k] * Bt[c][k]; A [KPAD][KPAD] f16, Bt [NC][KPAD].
// Round-8 single-buffer form (proven): the round-9 explicit double-buffer
// REGRESSED (+6%) — compiler can't disambiguate in-flight global_load_lds
// writes to buf^1 from ds_reads of buf, and orders them conservatively.
// ---------------------------------------------------------------------------
__global__ __launch_bounds__(256) void k_gemm_f16(const f16* __restrict__ A,
                                                  const f16* __restrict__ Bt,
                                                  f16* __restrict__ C, int NC) {
    __shared__ f16 Als[128 * 32];
    __shared__ f16 Bls[128 * 32];
    int tid = threadIdx.x;
    int w = tid >> 6, l = tid & 63;
    int wr = w >> 1, wc = w & 1;
    int row0 = blockIdx.y * 128;
    int col0 = blockIdx.x * 128;
    int rr = l >> 2;
    int cc = (l & 3) * 8;
    int lr = l & 15, lg = l >> 4;

    const f16* a0 = A + (size_t)(row0 + w * 32 + rr) * KPAD + cc;
    const f16* a1 = a0 + (size_t)16 * KPAD;
    const f16* b0 = Bt + (size_t)(col0 + w * 32 + rr) * KPAD + cc;
    const f16* b1 = b0 + (size_t)16 * KPAD;
    f16* la0 = &Als[(w * 32) * 32];
    f16* la1 = &Als[(w * 32 + 16) * 32];
    f16* lb0 = &Bls[(w * 32) * 32];
    f16* lb1 = &Bls[(w * 32 + 16) * 32];

    f32x4 acc[4][4];
#pragma unroll
    for (int m = 0; m < 4; ++m)
#pragma unroll
        for (int n = 0; n < 4; ++n) acc[m][n] = (f32x4)(0.f);

    for (int kt = 0; kt < KPAD / 32; ++kt) {
        int k0 = kt * 32;
        gload16(a0 + k0, la0);
        gload16(a1 + k0, la1);
        gload16(b0 + k0, lb0);
        gload16(b1 + k0, lb1);
        __syncthreads();
        f16x8 af[4], bf[4];
#pragma unroll
        for (int m = 0; m < 4; ++m)
            af[m] = *(const f16x8*)&Als[(wr * 64 + m * 16 + lr) * 32 + lg * 8];
#pragma unroll
        for (int n = 0; n < 4; ++n)
            bf[n] = *(const f16x8*)&Bls[(wc * 64 + n * 16 + lr) * 32 + lg * 8];
#pragma unroll
        for (int m = 0; m < 4; ++m)
#pragma unroll
            for (int n = 0; n < 4; ++n)
                acc[m][n] = __builtin_amdgcn_mfma_f32_16x16x32_f16(af[m], bf[n], acc[m][n], 0, 0, 0);
        __syncthreads();
    }

#pragma unroll
    for (int m = 0; m < 4; ++m) {
        int gr0 = row0 + wr * 64 + m * 16 + lg * 4;
#pragma unroll
        for (int n = 0; n < 4; ++n) {
            int gc = col0 + wc * 64 + n * 16 + lr;
            f32x4 v = acc[m][n];
#pragma unroll
            for (int q = 0; q < 4; ++q) {
                int r = gr0 + q;
                if (r < N_NODES) C[(size_t)r * NC + gc] = (f16)v[q];
            }
        }
    }
}

// ---------------------------------------------------------------------------
// Gate apply (MFMA): per (n,dir), C[64 b][128 o] = inp[64][160] x WgT[n][128][160]
// ---------------------------------------------------------------------------
__global__ __launch_bounds__(256) void k_apply_gate(
    const float* __restrict__ x, const f16* __restrict__ Hh,
    const f16* __restrict__ SXh, const f16* __restrict__ SHh,
    const f16* __restrict__ WgT,
    f16* __restrict__ Zh, f16* __restrict__ RHh, int t, int first) {
    int n = blockIdx.x, dir = blockIdx.y;
    int tid = threadIdx.x;
    int tt = dir ? (T_STEPS - 1 - t) : t;
    __shared__ f16 inpA[64 * ASTR];

    const f16* hhrow = Hh + (size_t)n * NCOLS + dir * 4096;
    const f16* shrow = SHh + (size_t)n * NCOLS + dir * 4096;

#pragma unroll
    for (int it = 0; it < 8; ++it) {
        int i2 = tid + it * 256;
        int b = i2 >> 5, jp = i2 & 31;
        *(unsigned*)&inpA[b * ASTR + 2 + 2 * jp] = *(const unsigned*)&hhrow[b * 64 + 2 * jp];
        *(unsigned*)&inpA[b * ASTR + 68 + 2 * jp] =
            first ? 0u : *(const unsigned*)&shrow[b * 64 + 2 * jp];
    }
    if (tid < 128) {
        int b = tid >> 1, i = tid & 1;
        inpA[b * ASTR + i] = (f16)x[(((size_t)b * T_STEPS + tt) * N_NODES + n) * 2 + i];
        inpA[b * ASTR + 66 + i] = SXh[(size_t)n * XCOLS + tt * 128 + b * 2 + i];
    }
    for (int idx = tid; idx < 64 * 14; idx += 256) {
        int b = idx / 14, p = idx % 14;
        *(unsigned*)&inpA[b * ASTR + 132 + 2 * p] = (p == 0) ? 0x00003C00u : 0u;
    }
    __syncthreads();

    int w = tid >> 6, l = tid & 63;
    int lr = l & 15, lg = l >> 4;
    int o0 = w * 32;
    const f16* wbase = WgT + (size_t)(dir * N_NODES + n) * GOSTR;

    f32x4 acc[4][2];
#pragma unroll
    for (int m = 0; m < 4; ++m)
#pragma unroll
        for (int j = 0; j < 2; ++j) acc[m][j] = (f32x4)(0.f);

#pragma unroll
    for (int kt = 0; kt < 5; ++kt) {
        int k0 = kt * 32 + lg * 8;
        f16x8 af[4], bf[2];
#pragma unroll
        for (int m = 0; m < 4; ++m)
            af[m] = *(const f16x8*)&inpA[(m * 16 + lr) * ASTR + k0];
#pragma unroll
        for (int j = 0; j < 2; ++j)
            bf[j] = *(const f16x8*)&wbase[(size_t)(o0 + j * 16 + lr) * WSTR + k0];
#pragma unroll
        for (int m = 0; m < 4; ++m)
#pragma unroll
            for (int j = 0; j < 2; ++j)
                acc[m][j] = __builtin_amdgcn_mfma_f32_16x16x32_f16(af[m], bf[j], acc[m][j], 0, 0, 0);
    }

    f16* zrow = Zh + (size_t)(dir * N_NODES + n) * 4096;
    f16* rhrow = RHh + (size_t)n * NCOLS + dir * 4096;
#pragma unroll
    for (int j = 0; j < 2; ++j) {
        int o = o0 + j * 16 + lr;
        if (o < 64) {
#pragma unroll
            for (int m = 0; m < 4; ++m) {
                int b0 = m * 16 + lg * 4;
                f32x4 v = acc[m][j];
#pragma unroll
                for (int q = 0; q < 4; ++q)
                    zrow[(b0 + q) * 64 + o] = (f16)(1.f / (1.f + expf(-v[q])));
            }
        } else {
            int jj = o - 64;
#pragma unroll
            for (int m = 0; m < 4; ++m) {
                int b0 = m * 16 + lg * 4;
                f32x4 v = acc[m][j];
#pragma unroll
                for (int q = 0; q < 4; ++q) {
                    float r = 1.f / (1.f + expf(-v[q]));
                    rhrow[(b0 + q) * 64 + jj] =
                        (f16)(r * (float)hhrow[(b0 + q) * 64 + jj]);
                }
            }
        }
    }
}

// ---------------------------------------------------------------------------
// Candidate apply (MFMA): per (n,dir), C[64 b][64 o]. fp16 state update.
// last=1 (t==T-1): skip the Hh state write (no consumer afterwards).
// ---------------------------------------------------------------------------
__global__ __launch_bounds__(256) void k_apply_cand(
    const float* __restrict__ x, const f16* __restrict__ SXh,
    const f16* __restrict__ SRHh, const f16* __restrict__ RHh,
    const f16* __restrict__ WcT, const f16* __restrict__ Zh,
    f16* __restrict__ Hh, float* __restrict__ out, int t, int last) {
    int n = blockIdx.x, dir = blockIdx.y;
    int tid = threadIdx.x;
    int tt = dir ? (T_STEPS - 1 - t) : t;
    __shared__ f16 inpA[64 * ASTR];

    const f16* rhrow = RHh + (size_t)n * NCOLS + dir * 4096;
    const f16* srhrow = SRHh + (size_t)n * NCOLS + dir * 4096;

#pragma unroll
    for (int it = 0; it < 8; ++it) {
        int i2 = tid + it * 256;
        int b = i2 >> 5, jp = i2 & 31;
        *(unsigned*)&inpA[b * ASTR + 2 + 2 * jp] = *(const unsigned*)&rhrow[b * 64 + 2 * jp];
        *(unsigned*)&inpA[b * ASTR + 68 + 2 * jp] = *(const unsigned*)&srhrow[b * 64 + 2 * jp];
    }
    if (tid < 128) {
        int b = tid >> 1, i = tid & 1;
        inpA[b * ASTR + i] = (f16)x[(((size_t)b * T_STEPS + tt) * N_NODES + n) * 2 + i];
        inpA[b * ASTR + 66 + i] = SXh[(size_t)n * XCOLS + tt * 128 + b * 2 + i];
    }
    for (int idx = tid; idx < 64 * 14; idx += 256) {
        int b = idx / 14, p = idx % 14;
        *(unsigned*)&inpA[b * ASTR + 132 + 2 * p] = (p == 0) ? 0x00003C00u : 0u;
    }
    __syncthreads();

    int w = tid >> 6, l = tid & 63;
    int lr = l & 15, lg = l >> 4;
    const f16* wbase = WcT + (size_t)(dir * N_NODES + n) * COSTR;

    f32x4 acc[4];
#pragma unroll
    for (int j = 0; j < 4; ++j) acc[j] = (f32x4)(0.f);

#pragma unroll
    for (int kt = 0; kt < 5; ++kt) {
        int k0 = kt * 32 + lg * 8;
        f16x8 af = *(const f16x8*)&inpA[(w * 16 + lr) * ASTR + k0];
        f16x8 bf[4];
#pragma unroll
        for (int j = 0; j < 4; ++j)
            bf[j] = *(const f16x8*)&wbase[(size_t)(j * 16 + lr) * WSTR + k0];
#pragma unroll
        for (int j = 0; j < 4; ++j)
            acc[j] = __builtin_amdgcn_mfma_f32_16x16x32_f16(af, bf[j], acc[j], 0, 0, 0);
    }

    const f16* zrow = Zh + (size_t)(dir * N_NODES + n) * 4096;
    f16* hhrow = Hh + (size_t)n * NCOLS + dir * 4096;
#pragma unroll
    for (int j = 0; j < 4; ++j) {
        int o = j * 16 + lr;
        f32x4 v = acc[j];
#pragma unroll
        for (int q = 0; q < 4; ++q) {
            int b = w * 16 + lg * 4 + q;
            float hc = tanhf(v[q]);
            float zv = (float)zrow[b * 64 + o];
            float hp = (float)hhrow[b * 64 + o];
            float hn = zv * hp + (1.f - zv) * hc;
            if (!last) hhrow[b * 64 + o] = (f16)hn;
            out[(((size_t)b * T_STEPS + t) * N_NODES + n) * 128 + dir * 64 + o] = hn;
        }
    }
}

// ---------------------------------------------------------------------------
extern "C" void kernel_launch(void* const* d_in, const int* in_sizes, int n_in,
                              void* d_out, int out_size, void* d_ws, size_t ws_size,
                              hipStream_t stream) {
    const float* x    = (const float*)d_in[0];
    const float* adj  = (const float*)d_in[1];
    const float* E    = (const float*)d_in[2];
    const float* Wg_f = (const float*)d_in[3];
    const float* bg_f = (const float*)d_in[4];
    const float* Wc_f = (const float*)d_in[5];
    const float* bc_f = (const float*)d_in[6];
    const float* Wg_b = (const float*)d_in[7];
    const float* bg_b = (const float*)d_in[8];
    const float* Wc_b = (const float*)d_in[9];
    const float* bc_b = (const float*)d_in[10];
    float* out = (float*)d_out;

    size_t off = 0;
    auto alloc = [&](size_t bytes) {
        void* p = (char*)d_ws + off;
        off += (bytes + 255) & ~(size_t)255;
        return p;
    };
    f16*   Sh   = (f16*)alloc((size_t)KPAD * KPAD * 2);
    f16*   XTt  = (f16*)alloc((size_t)XCOLS * KPAD * 2);
    f16*   SXh  = (f16*)alloc((size_t)N_NODES * XCOLS * 2);
    f16*   Hh   = (f16*)alloc((size_t)N_NODES * NCOLS * 2);
    f16*   SHh  = (f16*)alloc((size_t)N_NODES * NCOLS * 2);
    f16*   RHh  = (f16*)alloc((size_t)N_NODES * NCOLS * 2);
    f16*   Zh   = (f16*)alloc((size_t)N_NODES * NCOLS * 2);
    f16*   HBt  = (f16*)alloc((size_t)NCOLS * KPAD * 2);
    f16*   RHBt = (f16*)alloc((size_t)NCOLS * KPAD * 2);
    f16*   WgT  = (f16*)alloc((size_t)2 * N_NODES * GOSTR * 2);
    f16*   WcT  = (f16*)alloc((size_t)2 * N_NODES * COSTR * 2);
    // Overlay: Wg_r/Wc_r (2.46 MB, consumed by k_buildW2 before the time loop)
    // live inside RHBt (14.68 MB), first written at t=0's transpose, after
    // buildW2. Keeps workspace within the replay-proven footprint (r6 lesson).
    float* Wg_r = (float*)RHBt;
    float* Wc_r = Wg_r + (size_t)2 * DE * GOSTR;

    hipMemsetAsync(Sh, 0, (size_t)KPAD * KPAD * 2, stream);
    hipMemsetAsync(XTt, 0, (size_t)XCOLS * KPAD * 2, stream);
    hipMemsetAsync(Hh, 0, (size_t)N_NODES * NCOLS * 2, stream);

    k_computeS<<<N_NODES, 256, 0, stream>>>(E, adj, Sh);
    {
        int total = XCOLS * N_NODES;
        k_buildXT<<<(total + 255) / 256, 256, 0, stream>>>(x, XTt);
    }
    {
        int total = 2 * DE * (GOSTR + COSTR);
        k_reorgW<<<(total + 255) / 256, 256, 0, stream>>>(Wg_f, Wg_b, Wc_f, Wc_b,
                                                          bg_f, bg_b, bc_f, bc_b,
                                                          Wg_r, Wc_r);
    }
    k_buildW2<<<dim3(56, 2, 6), 256, 0, stream>>>(E, Wg_r, Wc_r, WgT, WcT);
    k_gemm_f16<<<dim3(XCOLS / 128, 7), 256, 0, stream>>>(Sh, XTt, SXh, XCOLS);

    dim3 gnode(N_NODES, 2);
    dim3 gmain(NCOLS / 128, 7);
    dim3 gtr(NCOLS / 64, KPAD / 64);
    for (int t = 0; t < T_STEPS; ++t) {
        if (t > 0)
            k_gemm_f16<<<gmain, 256, 0, stream>>>(Sh, HBt, SHh, NCOLS);
        k_apply_gate<<<gnode, 256, 0, stream>>>(x, Hh, SXh, SHh, WgT,
                                                Zh, RHh, t, t == 0 ? 1 : 0);
        k_transpose<<<gtr, 256, 0, stream>>>(RHh, RHBt);
        k_gemm_f16<<<gmain, 256, 0, stream>>>(Sh, RHBt, SHh, NCOLS);
        k_apply_cand<<<gnode, 256, 0, stream>>>(x, SXh, SHh, RHh, WcT,
                                                Zh, Hh, out, t,
                                                t == T_STEPS - 1 ? 1 : 0);
        if (t < T_STEPS - 1)
            k_transpose<<<gtr, 256, 0, stream>>>(Hh, HBt);
    }
}

// Round 11
// 1540.986 us; speedup vs baseline: 1.0796x; 1.0213x over previous
//
#include <hip/hip_runtime.h>
#include <math.h>

#define N_NODES 883
#define KPAD 896
#define T_STEPS 12
#define DE 10
#define KI 132          // CHEB_K * (DIN + DOUT) = 2 * 66
#define NCOLS 8192      // 2 dirs * 64 batch * 64 hidden
#define XCOLS 1536      // T * B * DIN
#define WSTR 160        // weight row stride (k padded 132 -> 160; k=132 = bias col)
#define ASTR 168        // LDS inp row stride (fp16 elems)
#define GOSTR (128 * WSTR)   // 20480 gate weight elems per (n,dir)
#define COSTR (64 * WSTR)    // 10240 cand weight elems per (n,dir)
#define BK 64           // GEMM K-step (was 32; halves barrier/latency count)

typedef _Float16 f16;
typedef __attribute__((ext_vector_type(2))) _Float16 f16x2;
typedef __attribute__((ext_vector_type(4))) _Float16 f16x4;
typedef __attribute__((ext_vector_type(8))) _Float16 f16x8;
typedef __attribute__((ext_vector_type(4))) float f32x4;

__device__ inline void gload16(const void* g, void* l) {
    __builtin_amdgcn_global_load_lds(
        (const __attribute__((address_space(1))) unsigned int*)g,
        (__attribute__((address_space(3))) unsigned int*)l, 16, 0, 0);
}

// ---------------------------------------------------------------------------
// Sh[n][m] (fp16, padded to 896x896) = softmax(relu(E E^T), axis=1) + adj
// ---------------------------------------------------------------------------
__global__ __launch_bounds__(256) void k_computeS(const float* __restrict__ E,
                                                  const float* __restrict__ adj,
                                                  f16* __restrict__ Sh) {
    int n = blockIdx.x;
    int tid = threadIdx.x;
    __shared__ float l[N_NODES];
    __shared__ float red[8];
    float En[DE];
#pragma unroll
    for (int d = 0; d < DE; ++d) En[d] = E[n * DE + d];

    float lmax = -1e30f;
    for (int m = tid; m < N_NODES; m += 256) {
        float dot = 0.f;
#pragma unroll
        for (int d = 0; d < DE; ++d) dot += En[d] * E[m * DE + d];
        dot = fmaxf(dot, 0.f);
        l[m] = dot;
        lmax = fmaxf(lmax, dot);
    }
    int wave = tid >> 6, lane = tid & 63;
    for (int off = 32; off > 0; off >>= 1) lmax = fmaxf(lmax, __shfl_down(lmax, off));
    if (lane == 0) red[wave] = lmax;
    __syncthreads();
    float gmax = fmaxf(fmaxf(red[0], red[1]), fmaxf(red[2], red[3]));
    __syncthreads();

    float lsum = 0.f;
    for (int m = tid; m < N_NODES; m += 256) {
        float e = expf(l[m] - gmax);
        l[m] = e;
        lsum += e;
    }
    for (int off = 32; off > 0; off >>= 1) lsum += __shfl_down(lsum, off);
    if (lane == 0) red[wave] = lsum;
    __syncthreads();
    float inv = 1.0f / (red[0] + red[1] + red[2] + red[3]);
    for (int m = tid; m < N_NODES; m += 256) {
        Sh[(size_t)n * KPAD + m] = (f16)(l[m] * inv + adj[(size_t)n * N_NODES + m]);
    }
}

// ---------------------------------------------------------------------------
// XTt[c][m] (fp16, [1536][896]) = x[b,t,m,i] with c=(t*64+b)*2+i
// ---------------------------------------------------------------------------
__global__ void k_buildXT(const float* __restrict__ x, f16* __restrict__ XTt) {
    int idx = blockIdx.x * blockDim.x + threadIdx.x;
    if (idx >= XCOLS * N_NODES) return;
    int m = idx % N_NODES;
    int c = idx / N_NODES;
    int t = c >> 7;
    int b = (c >> 1) & 63;
    int i = c & 1;
    XTt[(size_t)c * KPAD + m] = (f16)x[(((size_t)b * T_STEPS + t) * N_NODES + m) * 2 + i];
}

// ---------------------------------------------------------------------------
// Repack pooled weights into output flat order; k==KI carries the pooled BIAS
// (the applies feed inp[k=132]=1.0 so bias rides through the MFMA).
// ---------------------------------------------------------------------------
__global__ void k_reorgW(const float* __restrict__ Wg_f, const float* __restrict__ Wg_b,
                         const float* __restrict__ Wc_f, const float* __restrict__ Wc_b,
                         const float* __restrict__ bg_f, const float* __restrict__ bg_b,
                         const float* __restrict__ bc_f, const float* __restrict__ bc_b,
                         float* __restrict__ Wg_r, float* __restrict__ Wc_r) {
    const int GTOT = 2 * DE * GOSTR;   // 409600
    const int CTOT = 2 * DE * COSTR;   // 204800
    int idx = blockIdx.x * blockDim.x + threadIdx.x;
    if (idx < GTOT) {
        int k = idx % WSTR;
        int o = (idx / WSTR) & 127;
        int d = (idx / GOSTR) % DE;
        int dir = idx / (DE * GOSTR);
        float v = 0.f;
        if (k < KI) {
            const float* W = dir ? Wg_b : Wg_f;
            int kc = k / 66, i = k % 66;
            v = W[(((size_t)d * 2 + kc) * 66 + i) * 128 + o];
        } else if (k == KI) {
            v = (dir ? bg_b : bg_f)[d * 128 + o];
        }
        Wg_r[idx] = v;
    } else if (idx < GTOT + CTOT) {
        int j = idx - GTOT;
        int k = j % WSTR;
        int o = (j / WSTR) & 63;
        int d = (j / COSTR) % DE;
        int dir = j / (DE * COSTR);
        float v = 0.f;
        if (k < KI) {
            const float* W = dir ? Wc_b : Wc_f;
            int kc = k / 66, i = k % 66;
            v = W[(((size_t)d * 2 + kc) * 66 + i) * 64 + o];
        } else if (k == KI) {
            v = (dir ? bc_b : bc_f)[d * 64 + o];
        }
        Wc_r[j] = v;
    }
}

// ---------------------------------------------------------------------------
// Per-node weights from repacked pools. Block = (16-node group, dir, f-slice).
// ---------------------------------------------------------------------------
__global__ __launch_bounds__(256) void k_buildW2(
    const float* __restrict__ E,
    const float* __restrict__ Wg_r, const float* __restrict__ Wc_r,
    f16* __restrict__ WgT, f16* __restrict__ WcT) {
    int grp = blockIdx.x, dir = blockIdx.y, z = blockIdx.z;
    int n0 = grp * 16;
    int tid = threadIdx.x;
    __shared__ float Es[16][DE];
    if (tid < 16 * DE) {
        int nn = tid / DE, d = tid % DE;
        int n = n0 + nn;
        Es[nn][d] = (n < N_NODES) ? E[n * DE + d] : 0.f;
    }
    __syncthreads();

    bool gate = z < 4;
    const float* src = gate ? (Wg_r + (size_t)dir * DE * GOSTR)
                            : (Wc_r + (size_t)dir * DE * COSTR);
    f16* dst = gate ? WgT : WcT;
    int ostr = gate ? GOSTR : COSTR;
    int slot0 = gate ? z * 1280 : (z - 4) * 1280;

#pragma unroll
    for (int it = 0; it < 5; ++it) {
        int f = (slot0 + it * 256 + tid) * 4;
        float4 v[DE];
#pragma unroll
        for (int d = 0; d < DE; ++d)
            v[d] = *(const float4*)&src[(size_t)d * ostr + f];
#pragma unroll
        for (int nn = 0; nn < 16; ++nn) {
            int n = n0 + nn;
            if (n >= N_NODES) break;
            float a0 = 0.f, a1 = 0.f, a2 = 0.f, a3 = 0.f;
#pragma unroll
            for (int d = 0; d < DE; ++d) {
                float e = Es[nn][d];
                a0 += e * v[d].x; a1 += e * v[d].y;
                a2 += e * v[d].z; a3 += e * v[d].w;
            }
            f16x4 r = {(f16)a0, (f16)a1, (f16)a2, (f16)a3};
            *(f16x4*)&dst[(size_t)(dir * N_NODES + n) * ostr + f] = r;
        }
    }
}

// ---------------------------------------------------------------------------
// VT[c][n'] (f16 [NCOLS][KPAD]) = V[n][c] (f16 [N_NODES][NCOLS]); zero-pads n'.
// ---------------------------------------------------------------------------
__global__ __launch_bounds__(256) void k_transpose(const f16* __restrict__ V,
                                                   f16* __restrict__ VT) {
    __shared__ f16 tile[64][66];
    int c0 = blockIdx.x * 64;
    int n0 = blockIdx.y * 64;
    int tid = threadIdx.x;
#pragma unroll
    for (int it = 0; it < 2; ++it) {
        int chunk = tid + it * 256;
        int r = chunk >> 3, g = chunk & 7;
        int n = n0 + r;
        f16 tmp[8];
        if (n < N_NODES) {
            f16x8 v = *(const f16x8*)&V[(size_t)n * NCOLS + c0 + g * 8];
#pragma unroll
            for (int j = 0; j < 8; ++j) tmp[j] = v[j];
        } else {
#pragma unroll
            for (int j = 0; j < 8; ++j) tmp[j] = (f16)0.f;
        }
#pragma unroll
        for (int j = 0; j < 8; ++j) tile[g * 8 + j][r] = tmp[j];
    }
    __syncthreads();
#pragma unroll
    for (int it = 0; it < 2; ++it) {
        int chunk = tid + it * 256;
        int cc = chunk >> 3, m = chunk & 7;
        f16x8 v;
#pragma unroll
        for (int j = 0; j < 8; ++j) v[j] = tile[cc][m * 8 + j];
        *(f16x8*)&VT[(size_t)(c0 + cc) * KPAD + n0 + m * 8] = v;
    }
}

// ---------------------------------------------------------------------------
// C[r][c] (fp16) = sum_k A[r][k] * Bt[c][k]; A [KPAD][KPAD], Bt [NC][KPAD].
// BK=64 K-step: 14 iterations (vs 28) -> half the serialized
// {gload-latency + barrier-drain} exposures (the dominant cost; MFMA ~4%).
// Linear [128][64] LDS would put all 16 lr-lanes of a ds_read_b128 in one
// 4-bank group, so T2 XOR-swizzle (slot ^= row&7) is folded in, applied
// BOTH sides (rule #21): pre-swizzled GLOBAL source slot in staging
// (gload_lds writes LDS linearly) + swizzled slot on fragment read.
// Same total staging bytes, same MFMA accumulation order (bitwise-identical C).
// ---------------------------------------------------------------------------
__global__ __launch_bounds__(256) void k_gemm_f16(const f16* __restrict__ A,
                                                  const f16* __restrict__ Bt,
                                                  f16* __restrict__ C, int NC) {
    __shared__ f16 Als[128 * BK];
    __shared__ f16 Bls[128 * BK];
    int tid = threadIdx.x;
    int w = tid >> 6, l = tid & 63;
    int wr = w >> 1, wc = w & 1;
    int row0 = blockIdx.y * 128;
    int col0 = blockIdx.x * 128;
    int lr = l & 15, lg = l >> 4;

    // staging geometry: wave w stages rows w*32..+31 (4 chunks x 8 rows);
    // lane l covers chunk-row (l>>3), 16B slot (l&7); source slot XOR-swizzled.
    int sr = l >> 3;                    // row within 8-row chunk == row&7
    int gslot = (l & 7) ^ sr;           // pre-swizzled global 16B slot
    const f16* ga = A + (size_t)(row0 + w * 32 + sr) * KPAD + gslot * 8;
    const f16* gb = Bt + (size_t)(col0 + w * 32 + sr) * KPAD + gslot * 8;

    f32x4 acc[4][4];
#pragma unroll
    for (int m = 0; m < 4; ++m)
#pragma unroll
        for (int n = 0; n < 4; ++n) acc[m][n] = (f32x4)(0.f);

    for (int kt = 0; kt < KPAD / BK; ++kt) {
        int k0 = kt * BK;
#pragma unroll
        for (int c = 0; c < 4; ++c) {
            gload16(ga + (size_t)(c * 8) * KPAD + k0, &Als[(w * 32 + c * 8) * BK]);
            gload16(gb + (size_t)(c * 8) * KPAD + k0, &Bls[(w * 32 + c * 8) * BK]);
        }
        __syncthreads();
#pragma unroll
        for (int ks = 0; ks < 2; ++ks) {
            f16x8 af[4], bf[4];
#pragma unroll
            for (int m = 0; m < 4; ++m) {
                int row = wr * 64 + m * 16 + lr;
                int slot = (ks * 4 + lg) ^ (lr & 7);
                af[m] = *(const f16x8*)&Als[row * BK + slot * 8];
            }
#pragma unroll
            for (int n = 0; n < 4; ++n) {
                int row = wc * 64 + n * 16 + lr;
                int slot = (ks * 4 + lg) ^ (lr & 7);
                bf[n] = *(const f16x8*)&Bls[row * BK + slot * 8];
            }
#pragma unroll
            for (int m = 0; m < 4; ++m)
#pragma unroll
                for (int n = 0; n < 4; ++n)
                    acc[m][n] = __builtin_amdgcn_mfma_f32_16x16x32_f16(af[m], bf[n], acc[m][n], 0, 0, 0);
        }
        __syncthreads();
    }

#pragma unroll
    for (int m = 0; m < 4; ++m) {
        int gr0 = row0 + wr * 64 + m * 16 + lg * 4;
#pragma unroll
        for (int n = 0; n < 4; ++n) {
            int gc = col0 + wc * 64 + n * 16 + lr;
            f32x4 v = acc[m][n];
#pragma unroll
            for (int q = 0; q < 4; ++q) {
                int r = gr0 + q;
                if (r < N_NODES) C[(size_t)r * NC + gc] = (f16)v[q];
            }
        }
    }
}

// ---------------------------------------------------------------------------
// Gate apply (MFMA): per (n,dir), C[64 b][128 o] = inp[64][160] x WgT[n][128][160]
// ---------------------------------------------------------------------------
__global__ __launch_bounds__(256) void k_apply_gate(
    const float* __restrict__ x, const f16* __restrict__ Hh,
    const f16* __restrict__ SXh, const f16* __restrict__ SHh,
    const f16* __restrict__ WgT,
    f16* __restrict__ Zh, f16* __restrict__ RHh, int t, int first) {
    int n = blockIdx.x, dir = blockIdx.y;
    int tid = threadIdx.x;
    int tt = dir ? (T_STEPS - 1 - t) : t;
    __shared__ f16 inpA[64 * ASTR];

    const f16* hhrow = Hh + (size_t)n * NCOLS + dir * 4096;
    const f16* shrow = SHh + (size_t)n * NCOLS + dir * 4096;

#pragma unroll
    for (int it = 0; it < 8; ++it) {
        int i2 = tid + it * 256;
        int b = i2 >> 5, jp = i2 & 31;
        *(unsigned*)&inpA[b * ASTR + 2 + 2 * jp] = *(const unsigned*)&hhrow[b * 64 + 2 * jp];
        *(unsigned*)&inpA[b * ASTR + 68 + 2 * jp] =
            first ? 0u : *(const unsigned*)&shrow[b * 64 + 2 * jp];
    }
    if (tid < 128) {
        int b = tid >> 1, i = tid & 1;
        inpA[b * ASTR + i] = (f16)x[(((size_t)b * T_STEPS + tt) * N_NODES + n) * 2 + i];
        inpA[b * ASTR + 66 + i] = SXh[(size_t)n * XCOLS + tt * 128 + b * 2 + i];
    }
    for (int idx = tid; idx < 64 * 14; idx += 256) {
        int b = idx / 14, p = idx % 14;
        *(unsigned*)&inpA[b * ASTR + 132 + 2 * p] = (p == 0) ? 0x00003C00u : 0u;
    }
    __syncthreads();

    int w = tid >> 6, l = tid & 63;
    int lr = l & 15, lg = l >> 4;
    int o0 = w * 32;
    const f16* wbase = WgT + (size_t)(dir * N_NODES + n) * GOSTR;

    f32x4 acc[4][2];
#pragma unroll
    for (int m = 0; m < 4; ++m)
#pragma unroll
        for (int j = 0; j < 2; ++j) acc[m][j] = (f32x4)(0.f);

#pragma unroll
    for (int kt = 0; kt < 5; ++kt) {
        int k0 = kt * 32 + lg * 8;
        f16x8 af[4], bf[2];
#pragma unroll
        for (int m = 0; m < 4; ++m)
            af[m] = *(const f16x8*)&inpA[(m * 16 + lr) * ASTR + k0];
#pragma unroll
        for (int j = 0; j < 2; ++j)
            bf[j] = *(const f16x8*)&wbase[(size_t)(o0 + j * 16 + lr) * WSTR + k0];
#pragma unroll
        for (int m = 0; m < 4; ++m)
#pragma unroll
            for (int j = 0; j < 2; ++j)
                acc[m][j] = __builtin_amdgcn_mfma_f32_16x16x32_f16(af[m], bf[j], acc[m][j], 0, 0, 0);
    }

    f16* zrow = Zh + (size_t)(dir * N_NODES + n) * 4096;
    f16* rhrow = RHh + (size_t)n * NCOLS + dir * 4096;
#pragma unroll
    for (int j = 0; j < 2; ++j) {
        int o = o0 + j * 16 + lr;
        if (o < 64) {
#pragma unroll
            for (int m = 0; m < 4; ++m) {
                int b0 = m * 16 + lg * 4;
                f32x4 v = acc[m][j];
#pragma unroll
                for (int q = 0; q < 4; ++q)
                    zrow[(b0 + q) * 64 + o] = (f16)(1.f / (1.f + expf(-v[q])));
            }
        } else {
            int jj = o - 64;
#pragma unroll
            for (int m = 0; m < 4; ++m) {
                int b0 = m * 16 + lg * 4;
                f32x4 v = acc[m][j];
#pragma unroll
                for (int q = 0; q < 4; ++q) {
                    float r = 1.f / (1.f + expf(-v[q]));
                    rhrow[(b0 + q) * 64 + jj] =
                        (f16)(r * (float)hhrow[(b0 + q) * 64 + jj]);
                }
            }
        }
    }
}

// ---------------------------------------------------------------------------
// Candidate apply (MFMA): per (n,dir), C[64 b][64 o]. fp16 state update.
// last=1 (t==T-1): skip the Hh state write (no consumer afterwards).
// ---------------------------------------------------------------------------
__global__ __launch_bounds__(256) void k_apply_cand(
    const float* __restrict__ x, const f16* __restrict__ SXh,
    const f16* __restrict__ SRHh, const f16* __restrict__ RHh,
    const f16* __restrict__ WcT, const f16* __restrict__ Zh,
    f16* __restrict__ Hh, float* __restrict__ out, int t, int last) {
    int n = blockIdx.x, dir = blockIdx.y;
    int tid = threadIdx.x;
    int tt = dir ? (T_STEPS - 1 - t) : t;
    __shared__ f16 inpA[64 * ASTR];

    const f16* rhrow = RHh + (size_t)n * NCOLS + dir * 4096;
    const f16* srhrow = SRHh + (size_t)n * NCOLS + dir * 4096;

#pragma unroll
    for (int it = 0; it < 8; ++it) {
        int i2 = tid + it * 256;
        int b = i2 >> 5, jp = i2 & 31;
        *(unsigned*)&inpA[b * ASTR + 2 + 2 * jp] = *(const unsigned*)&rhrow[b * 64 + 2 * jp];
        *(unsigned*)&inpA[b * ASTR + 68 + 2 * jp] = *(const unsigned*)&srhrow[b * 64 + 2 * jp];
    }
    if (tid < 128) {
        int b = tid >> 1, i = tid & 1;
        inpA[b * ASTR + i] = (f16)x[(((size_t)b * T_STEPS + tt) * N_NODES + n) * 2 + i];
        inpA[b * ASTR + 66 + i] = SXh[(size_t)n * XCOLS + tt * 128 + b * 2 + i];
    }
    for (int idx = tid; idx < 64 * 14; idx += 256) {
        int b = idx / 14, p = idx % 14;
        *(unsigned*)&inpA[b * ASTR + 132 + 2 * p] = (p == 0) ? 0x00003C00u : 0u;
    }
    __syncthreads();

    int w = tid >> 6, l = tid & 63;
    int lr = l & 15, lg = l >> 4;
    const f16* wbase = WcT + (size_t)(dir * N_NODES + n) * COSTR;

    f32x4 acc[4];
#pragma unroll
    for (int j = 0; j < 4; ++j) acc[j] = (f32x4)(0.f);

#pragma unroll
    for (int kt = 0; kt < 5; ++kt) {
        int k0 = kt * 32 + lg * 8;
        f16x8 af = *(const f16x8*)&inpA[(w * 16 + lr) * ASTR + k0];
        f16x8 bf[4];
#pragma unroll
        for (int j = 0; j < 4; ++j)
            bf[j] = *(const f16x8*)&wbase[(size_t)(j * 16 + lr) * WSTR + k0];
#pragma unroll
        for (int j = 0; j < 4; ++j)
            acc[j] = __builtin_amdgcn_mfma_f32_16x16x32_f16(af, bf[j], acc[j], 0, 0, 0);
    }

    const f16* zrow = Zh + (size_t)(dir * N_NODES + n) * 4096;
    f16* hhrow = Hh + (size_t)n * NCOLS + dir * 4096;
#pragma unroll
    for (int j = 0; j < 4; ++j) {
        int o = j * 16 + lr;
        f32x4 v = acc[j];
#pragma unroll
        for (int q = 0; q < 4; ++q) {
            int b = w * 16 + lg * 4 + q;
            float hc = tanhf(v[q]);
            float zv = (float)zrow[b * 64 + o];
            float hp = (float)hhrow[b * 64 + o];
            float hn = zv * hp + (1.f - zv) * hc;
            if (!last) hhrow[b * 64 + o] = (f16)hn;
            out[(((size_t)b * T_STEPS + t) * N_NODES + n) * 128 + dir * 64 + o] = hn;
        }
    }
}

// ---------------------------------------------------------------------------
extern "C" void kernel_launch(void* const* d_in, const int* in_sizes, int n_in,
                              void* d_out, int out_size, void* d_ws, size_t ws_size,
                              hipStream_t stream) {
    const float* x    = (const float*)d_in[0];
    const float* adj  = (const float*)d_in[1];
    const float* E    = (const float*)d_in[2];
    const float* Wg_f = (const float*)d_in[3];
    const float* bg_f = (const float*)d_in[4];
    const float* Wc_f = (const float*)d_in[5];
    const float* bc_f = (const float*)d_in[6];
    const float* Wg_b = (const float*)d_in[7];
    const float* bg_b = (const float*)d_in[8];
    const float* Wc_b = (const float*)d_in[9];
    const float* bc_b = (const float*)d_in[10];
    float* out = (float*)d_out;

    size_t off = 0;
    auto alloc = [&](size_t bytes) {
        void* p = (char*)d_ws + off;
        off += (bytes + 255) & ~(size_t)255;
        return p;
    };
    f16*   Sh   = (f16*)alloc((size_t)KPAD * KPAD * 2);
    f16*   XTt  = (f16*)alloc((size_t)XCOLS * KPAD * 2);
    f16*   SXh  = (f16*)alloc((size_t)N_NODES * XCOLS * 2);
    f16*   Hh   = (f16*)alloc((size_t)N_NODES * NCOLS * 2);
    f16*   SHh  = (f16*)alloc((size_t)N_NODES * NCOLS * 2);
    f16*   RHh  = (f16*)alloc((size_t)N_NODES * NCOLS * 2);
    f16*   Zh   = (f16*)alloc((size_t)N_NODES * NCOLS * 2);
    f16*   HBt  = (f16*)alloc((size_t)NCOLS * KPAD * 2);
    f16*   RHBt = (f16*)alloc((size_t)NCOLS * KPAD * 2);
    f16*   WgT  = (f16*)alloc((size_t)2 * N_NODES * GOSTR * 2);
    f16*   WcT  = (f16*)alloc((size_t)2 * N_NODES * COSTR * 2);
    // Overlay: Wg_r/Wc_r (2.46 MB, consumed by k_buildW2 before the time loop)
    // live inside RHBt (14.68 MB), first written at t=0's transpose, after
    // buildW2. Keeps workspace within the replay-proven footprint (r6 lesson).
    float* Wg_r = (float*)RHBt;
    float* Wc_r = Wg_r + (size_t)2 * DE * GOSTR;

    hipMemsetAsync(Sh, 0, (size_t)KPAD * KPAD * 2, stream);
    hipMemsetAsync(XTt, 0, (size_t)XCOLS * KPAD * 2, stream);
    hipMemsetAsync(Hh, 0, (size_t)N_NODES * NCOLS * 2, stream);

    k_computeS<<<N_NODES, 256, 0, stream>>>(E, adj, Sh);
    {
        int total = XCOLS * N_NODES;
        k_buildXT<<<(total + 255) / 256, 256, 0, stream>>>(x, XTt);
    }
    {
        int total = 2 * DE * (GOSTR + COSTR);
        k_reorgW<<<(total + 255) / 256, 256, 0, stream>>>(Wg_f, Wg_b, Wc_f, Wc_b,
                                                          bg_f, bg_b, bc_f, bc_b,
                                                          Wg_r, Wc_r);
    }
    k_buildW2<<<dim3(56, 2, 6), 256, 0, stream>>>(E, Wg_r, Wc_r, WgT, WcT);
    k_gemm_f16<<<dim3(XCOLS / 128, 7), 256, 0, stream>>>(Sh, XTt, SXh, XCOLS);

    dim3 gnode(N_NODES, 2);
    dim3 gmain(NCOLS / 128, 7);
    dim3 gtr(NCOLS / 64, KPAD / 64);
    for (int t = 0; t < T_STEPS; ++t) {
        if (t > 0)
            k_gemm_f16<<<gmain, 256, 0, stream>>>(Sh, HBt, SHh, NCOLS);
        k_apply_gate<<<gnode, 256, 0, stream>>>(x, Hh, SXh, SHh, WgT,
                                                Zh, RHh, t, t == 0 ? 1 : 0);
        k_transpose<<<gtr, 256, 0, stream>>>(RHh, RHBt);
        k_gemm_f16<<<gmain, 256, 0, stream>>>(Sh, RHBt, SHh, NCOLS);
        k_apply_cand<<<gnode, 256, 0, stream>>>(x, SXh, SHh, RHh, WcT,
                                                Zh, Hh, out, t,
                                                t == T_STEPS - 1 ? 1 : 0);
        if (t < T_STEPS - 1)
            k_transpose<<<gtr, 256, 0, stream>>>(Hh, HBt);
    }
}

// Round 12
// 1498.747 us; speedup vs baseline: 1.1100x; 1.0282x over previous
//
#include <hip/hip_runtime.h>
#include <math.h>

#define N_NODES 883
#define KPAD 896
#define T_STEPS 12
#define DE 10
#define KI 132          // CHEB_K * (DIN + DOUT) = 2 * 66
#define NCOLS 8192      // 2 dirs * 64 batch * 64 hidden
#define XCOLS 1536      // T * B * DIN
#define WSTR 160        // weight row stride (k padded 132 -> 160; k=132 = bias col)
#define ASTR 168        // LDS inp row stride (fp16 elems)
#define GOSTR (128 * WSTR)   // 20480 gate weight elems per (n,dir)
#define COSTR (64 * WSTR)    // 10240 cand weight elems per (n,dir)
#define BK 64           // GEMM K-step

typedef _Float16 f16;
typedef __attribute__((ext_vector_type(2))) _Float16 f16x2;
typedef __attribute__((ext_vector_type(4))) _Float16 f16x4;
typedef __attribute__((ext_vector_type(8))) _Float16 f16x8;
typedef __attribute__((ext_vector_type(4))) float f32x4;

__device__ inline void gload16(const void* g, void* l) {
    __builtin_amdgcn_global_load_lds(
        (const __attribute__((address_space(1))) unsigned int*)g,
        (__attribute__((address_space(3))) unsigned int*)l, 16, 0, 0);
}

// ---------------------------------------------------------------------------
// Sh[n][m] (fp16, padded to 896x896) = softmax(relu(E E^T), axis=1) + adj
// ---------------------------------------------------------------------------
__global__ __launch_bounds__(256) void k_computeS(const float* __restrict__ E,
                                                  const float* __restrict__ adj,
                                                  f16* __restrict__ Sh) {
    int n = blockIdx.x;
    int tid = threadIdx.x;
    __shared__ float l[N_NODES];
    __shared__ float red[8];
    float En[DE];
#pragma unroll
    for (int d = 0; d < DE; ++d) En[d] = E[n * DE + d];

    float lmax = -1e30f;
    for (int m = tid; m < N_NODES; m += 256) {
        float dot = 0.f;
#pragma unroll
        for (int d = 0; d < DE; ++d) dot += En[d] * E[m * DE + d];
        dot = fmaxf(dot, 0.f);
        l[m] = dot;
        lmax = fmaxf(lmax, dot);
    }
    int wave = tid >> 6, lane = tid & 63;
    for (int off = 32; off > 0; off >>= 1) lmax = fmaxf(lmax, __shfl_down(lmax, off));
    if (lane == 0) red[wave] = lmax;
    __syncthreads();
    float gmax = fmaxf(fmaxf(red[0], red[1]), fmaxf(red[2], red[3]));
    __syncthreads();

    float lsum = 0.f;
    for (int m = tid; m < N_NODES; m += 256) {
        float e = expf(l[m] - gmax);
        l[m] = e;
        lsum += e;
    }
    for (int off = 32; off > 0; off >>= 1) lsum += __shfl_down(lsum, off);
    if (lane == 0) red[wave] = lsum;
    __syncthreads();
    float inv = 1.0f / (red[0] + red[1] + red[2] + red[3]);
    for (int m = tid; m < N_NODES; m += 256) {
        Sh[(size_t)n * KPAD + m] = (f16)(l[m] * inv + adj[(size_t)n * N_NODES + m]);
    }
}

// ---------------------------------------------------------------------------
// XTt[c][m] (fp16, [1536][896]) = x[b,t,m,i] with c=(t*64+b)*2+i
// ---------------------------------------------------------------------------
__global__ void k_buildXT(const float* __restrict__ x, f16* __restrict__ XTt) {
    int idx = blockIdx.x * blockDim.x + threadIdx.x;
    if (idx >= XCOLS * N_NODES) return;
    int m = idx % N_NODES;
    int c = idx / N_NODES;
    int t = c >> 7;
    int b = (c >> 1) & 63;
    int i = c & 1;
    XTt[(size_t)c * KPAD + m] = (f16)x[(((size_t)b * T_STEPS + t) * N_NODES + m) * 2 + i];
}

// ---------------------------------------------------------------------------
// Repack pooled weights into output flat order; k==KI carries the pooled BIAS
// (the applies feed inp[k=132]=1.0 so bias rides through the MFMA).
// ---------------------------------------------------------------------------
__global__ void k_reorgW(const float* __restrict__ Wg_f, const float* __restrict__ Wg_b,
                         const float* __restrict__ Wc_f, const float* __restrict__ Wc_b,
                         const float* __restrict__ bg_f, const float* __restrict__ bg_b,
                         const float* __restrict__ bc_f, const float* __restrict__ bc_b,
                         float* __restrict__ Wg_r, float* __restrict__ Wc_r) {
    const int GTOT = 2 * DE * GOSTR;   // 409600
    const int CTOT = 2 * DE * COSTR;   // 204800
    int idx = blockIdx.x * blockDim.x + threadIdx.x;
    if (idx < GTOT) {
        int k = idx % WSTR;
        int o = (idx / WSTR) & 127;
        int d = (idx / GOSTR) % DE;
        int dir = idx / (DE * GOSTR);
        float v = 0.f;
        if (k < KI) {
            const float* W = dir ? Wg_b : Wg_f;
            int kc = k / 66, i = k % 66;
            v = W[(((size_t)d * 2 + kc) * 66 + i) * 128 + o];
        } else if (k == KI) {
            v = (dir ? bg_b : bg_f)[d * 128 + o];
        }
        Wg_r[idx] = v;
    } else if (idx < GTOT + CTOT) {
        int j = idx - GTOT;
        int k = j % WSTR;
        int o = (j / WSTR) & 63;
        int d = (j / COSTR) % DE;
        int dir = j / (DE * COSTR);
        float v = 0.f;
        if (k < KI) {
            const float* W = dir ? Wc_b : Wc_f;
            int kc = k / 66, i = k % 66;
            v = W[(((size_t)d * 2 + kc) * 66 + i) * 64 + o];
        } else if (k == KI) {
            v = (dir ? bc_b : bc_f)[d * 64 + o];
        }
        Wc_r[j] = v;
    }
}

// ---------------------------------------------------------------------------
// Per-node weights from repacked pools. Block = (16-node group, dir, f-slice).
// ---------------------------------------------------------------------------
__global__ __launch_bounds__(256) void k_buildW2(
    const float* __restrict__ E,
    const float* __restrict__ Wg_r, const float* __restrict__ Wc_r,
    f16* __restrict__ WgT, f16* __restrict__ WcT) {
    int grp = blockIdx.x, dir = blockIdx.y, z = blockIdx.z;
    int n0 = grp * 16;
    int tid = threadIdx.x;
    __shared__ float Es[16][DE];
    if (tid < 16 * DE) {
        int nn = tid / DE, d = tid % DE;
        int n = n0 + nn;
        Es[nn][d] = (n < N_NODES) ? E[n * DE + d] : 0.f;
    }
    __syncthreads();

    bool gate = z < 4;
    const float* src = gate ? (Wg_r + (size_t)dir * DE * GOSTR)
                            : (Wc_r + (size_t)dir * DE * COSTR);
    f16* dst = gate ? WgT : WcT;
    int ostr = gate ? GOSTR : COSTR;
    int slot0 = gate ? z * 1280 : (z - 4) * 1280;

#pragma unroll
    for (int it = 0; it < 5; ++it) {
        int f = (slot0 + it * 256 + tid) * 4;
        float4 v[DE];
#pragma unroll
        for (int d = 0; d < DE; ++d)
            v[d] = *(const float4*)&src[(size_t)d * ostr + f];
#pragma unroll
        for (int nn = 0; nn < 16; ++nn) {
            int n = n0 + nn;
            if (n >= N_NODES) break;
            float a0 = 0.f, a1 = 0.f, a2 = 0.f, a3 = 0.f;
#pragma unroll
            for (int d = 0; d < DE; ++d) {
                float e = Es[nn][d];
                a0 += e * v[d].x; a1 += e * v[d].y;
                a2 += e * v[d].z; a3 += e * v[d].w;
            }
            f16x4 r = {(f16)a0, (f16)a1, (f16)a2, (f16)a3};
            *(f16x4*)&dst[(size_t)(dir * N_NODES + n) * ostr + f] = r;
        }
    }
}

// ---------------------------------------------------------------------------
// VT[c][n'] (f16 [NCOLS][KPAD]) = V[n][c] (f16 [N_NODES][NCOLS]); zero-pads n'.
// ---------------------------------------------------------------------------
__global__ __launch_bounds__(256) void k_transpose(const f16* __restrict__ V,
                                                   f16* __restrict__ VT) {
    __shared__ f16 tile[64][66];
    int c0 = blockIdx.x * 64;
    int n0 = blockIdx.y * 64;
    int tid = threadIdx.x;
#pragma unroll
    for (int it = 0; it < 2; ++it) {
        int chunk = tid + it * 256;
        int r = chunk >> 3, g = chunk & 7;
        int n = n0 + r;
        f16 tmp[8];
        if (n < N_NODES) {
            f16x8 v = *(const f16x8*)&V[(size_t)n * NCOLS + c0 + g * 8];
#pragma unroll
            for (int j = 0; j < 8; ++j) tmp[j] = v[j];
        } else {
#pragma unroll
            for (int j = 0; j < 8; ++j) tmp[j] = (f16)0.f;
        }
#pragma unroll
        for (int j = 0; j < 8; ++j) tile[g * 8 + j][r] = tmp[j];
    }
    __syncthreads();
#pragma unroll
    for (int it = 0; it < 2; ++it) {
        int chunk = tid + it * 256;
        int cc = chunk >> 3, m = chunk & 7;
        f16x8 v;
#pragma unroll
        for (int j = 0; j < 8; ++j) v[j] = tile[cc][m * 8 + j];
        *(f16x8*)&VT[(size_t)(c0 + cc) * KPAD + n0 + m * 8] = v;
    }
}

// ---------------------------------------------------------------------------
// C[r][c] (fp16) = sum_k A[r][k] * Bt[c][k]; A [KPAD][KPAD], Bt [NC][KPAD].
// 128x64 tile, grid (NC/64, 7) = 896 blocks -> 3.5 blocks/CU (~3.5 waves/SIMD,
// 2x the 128x128 version): r9/r11 showed dbuf and fewer iterations don't help
// because load latency was TLP-exposed, not iteration-bound. Wave-tile 64x32.
// BK=64 with T2 XOR swizzle applied BOTH sides (rule #21): pre-swizzled global
// source slot in staging + swizzled slot on fragment read. K-order unchanged
// -> bitwise-identical C vs r11.
// ---------------------------------------------------------------------------
__global__ __launch_bounds__(256) void k_gemm_f16(const f16* __restrict__ A,
                                                  const f16* __restrict__ Bt,
                                                  f16* __restrict__ C, int NC) {
    __shared__ f16 Als[128 * BK];
    __shared__ f16 Bls[64 * BK];
    int tid = threadIdx.x;
    int w = tid >> 6, l = tid & 63;
    int wr = w >> 1, wc = w & 1;
    int row0 = blockIdx.y * 128;
    int col0 = blockIdx.x * 64;
    int lr = l & 15, lg = l >> 4;

    // staging: wave w stages A rows w*32..+31 (4 chunks x 8) and B rows
    // w*16..+15 (2 chunks x 8); lane l covers chunk-row (l>>3), swizzled slot.
    int sr = l >> 3;
    int gslot = (l & 7) ^ sr;
    const f16* ga = A + (size_t)(row0 + w * 32 + sr) * KPAD + gslot * 8;
    const f16* gb = Bt + (size_t)(col0 + w * 16 + sr) * KPAD + gslot * 8;

    f32x4 acc[4][2];
#pragma unroll
    for (int m = 0; m < 4; ++m)
#pragma unroll
        for (int n = 0; n < 2; ++n) acc[m][n] = (f32x4)(0.f);

    for (int kt = 0; kt < KPAD / BK; ++kt) {
        int k0 = kt * BK;
#pragma unroll
        for (int c = 0; c < 4; ++c)
            gload16(ga + (size_t)(c * 8) * KPAD + k0, &Als[(w * 32 + c * 8) * BK]);
#pragma unroll
        for (int c = 0; c < 2; ++c)
            gload16(gb + (size_t)(c * 8) * KPAD + k0, &Bls[(w * 16 + c * 8) * BK]);
        __syncthreads();
#pragma unroll
        for (int ks = 0; ks < 2; ++ks) {
            int slot = (ks * 4 + lg) ^ (lr & 7);
            f16x8 af[4], bf[2];
#pragma unroll
            for (int m = 0; m < 4; ++m)
                af[m] = *(const f16x8*)&Als[(wr * 64 + m * 16 + lr) * BK + slot * 8];
#pragma unroll
            for (int n = 0; n < 2; ++n)
                bf[n] = *(const f16x8*)&Bls[(wc * 32 + n * 16 + lr) * BK + slot * 8];
#pragma unroll
            for (int m = 0; m < 4; ++m)
#pragma unroll
                for (int n = 0; n < 2; ++n)
                    acc[m][n] = __builtin_amdgcn_mfma_f32_16x16x32_f16(af[m], bf[n], acc[m][n], 0, 0, 0);
        }
        __syncthreads();
    }

#pragma unroll
    for (int m = 0; m < 4; ++m) {
        int gr0 = row0 + wr * 64 + m * 16 + lg * 4;
#pragma unroll
        for (int n = 0; n < 2; ++n) {
            int gc = col0 + wc * 32 + n * 16 + lr;
            f32x4 v = acc[m][n];
#pragma unroll
            for (int q = 0; q < 4; ++q) {
                int r = gr0 + q;
                if (r < N_NODES) C[(size_t)r * NC + gc] = (f16)v[q];
            }
        }
    }
}

// ---------------------------------------------------------------------------
// Gate apply (MFMA): per (n,dir), C[64 b][128 o] = inp[64][160] x WgT[n][128][160]
// ---------------------------------------------------------------------------
__global__ __launch_bounds__(256) void k_apply_gate(
    const float* __restrict__ x, const f16* __restrict__ Hh,
    const f16* __restrict__ SXh, const f16* __restrict__ SHh,
    const f16* __restrict__ WgT,
    f16* __restrict__ Zh, f16* __restrict__ RHh, int t, int first) {
    int n = blockIdx.x, dir = blockIdx.y;
    int tid = threadIdx.x;
    int tt = dir ? (T_STEPS - 1 - t) : t;
    __shared__ f16 inpA[64 * ASTR];

    const f16* hhrow = Hh + (size_t)n * NCOLS + dir * 4096;
    const f16* shrow = SHh + (size_t)n * NCOLS + dir * 4096;

#pragma unroll
    for (int it = 0; it < 8; ++it) {
        int i2 = tid + it * 256;
        int b = i2 >> 5, jp = i2 & 31;
        *(unsigned*)&inpA[b * ASTR + 2 + 2 * jp] = *(const unsigned*)&hhrow[b * 64 + 2 * jp];
        *(unsigned*)&inpA[b * ASTR + 68 + 2 * jp] =
            first ? 0u : *(const unsigned*)&shrow[b * 64 + 2 * jp];
    }
    if (tid < 128) {
        int b = tid >> 1, i = tid & 1;
        inpA[b * ASTR + i] = (f16)x[(((size_t)b * T_STEPS + tt) * N_NODES + n) * 2 + i];
        inpA[b * ASTR + 66 + i] = SXh[(size_t)n * XCOLS + tt * 128 + b * 2 + i];
    }
    for (int idx = tid; idx < 64 * 14; idx += 256) {
        int b = idx / 14, p = idx % 14;
        *(unsigned*)&inpA[b * ASTR + 132 + 2 * p] = (p == 0) ? 0x00003C00u : 0u;
    }
    __syncthreads();

    int w = tid >> 6, l = tid & 63;
    int lr = l & 15, lg = l >> 4;
    int o0 = w * 32;
    const f16* wbase = WgT + (size_t)(dir * N_NODES + n) * GOSTR;

    f32x4 acc[4][2];
#pragma unroll
    for (int m = 0; m < 4; ++m)
#pragma unroll
        for (int j = 0; j < 2; ++j) acc[m][j] = (f32x4)(0.f);

#pragma unroll
    for (int kt = 0; kt < 5; ++kt) {
        int k0 = kt * 32 + lg * 8;
        f16x8 af[4], bf[2];
#pragma unroll
        for (int m = 0; m < 4; ++m)
            af[m] = *(const f16x8*)&inpA[(m * 16 + lr) * ASTR + k0];
#pragma unroll
        for (int j = 0; j < 2; ++j)
            bf[j] = *(const f16x8*)&wbase[(size_t)(o0 + j * 16 + lr) * WSTR + k0];
#pragma unroll
        for (int m = 0; m < 4; ++m)
#pragma unroll
            for (int j = 0; j < 2; ++j)
                acc[m][j] = __builtin_amdgcn_mfma_f32_16x16x32_f16(af[m], bf[j], acc[m][j], 0, 0, 0);
    }

    f16* zrow = Zh + (size_t)(dir * N_NODES + n) * 4096;
    f16* rhrow = RHh + (size_t)n * NCOLS + dir * 4096;
#pragma unroll
    for (int j = 0; j < 2; ++j) {
        int o = o0 + j * 16 + lr;
        if (o < 64) {
#pragma unroll
            for (int m = 0; m < 4; ++m) {
                int b0 = m * 16 + lg * 4;
                f32x4 v = acc[m][j];
#pragma unroll
                for (int q = 0; q < 4; ++q)
                    zrow[(b0 + q) * 64 + o] = (f16)(1.f / (1.f + expf(-v[q])));
            }
        } else {
            int jj = o - 64;
#pragma unroll
            for (int m = 0; m < 4; ++m) {
                int b0 = m * 16 + lg * 4;
                f32x4 v = acc[m][j];
#pragma unroll
                for (int q = 0; q < 4; ++q) {
                    float r = 1.f / (1.f + expf(-v[q]));
                    rhrow[(b0 + q) * 64 + jj] =
                        (f16)(r * (float)hhrow[(b0 + q) * 64 + jj]);
                }
            }
        }
    }
}

// ---------------------------------------------------------------------------
// Candidate apply (MFMA): per (n,dir), C[64 b][64 o]. fp16 state update.
// last=1 (t==T-1): skip the Hh state write (no consumer afterwards).
// ---------------------------------------------------------------------------
__global__ __launch_bounds__(256) void k_apply_cand(
    const float* __restrict__ x, const f16* __restrict__ SXh,
    const f16* __restrict__ SRHh, const f16* __restrict__ RHh,
    const f16* __restrict__ WcT, const f16* __restrict__ Zh,
    f16* __restrict__ Hh, float* __restrict__ out, int t, int last) {
    int n = blockIdx.x, dir = blockIdx.y;
    int tid = threadIdx.x;
    int tt = dir ? (T_STEPS - 1 - t) : t;
    __shared__ f16 inpA[64 * ASTR];

    const f16* rhrow = RHh + (size_t)n * NCOLS + dir * 4096;
    const f16* srhrow = SRHh + (size_t)n * NCOLS + dir * 4096;

#pragma unroll
    for (int it = 0; it < 8; ++it) {
        int i2 = tid + it * 256;
        int b = i2 >> 5, jp = i2 & 31;
        *(unsigned*)&inpA[b * ASTR + 2 + 2 * jp] = *(const unsigned*)&rhrow[b * 64 + 2 * jp];
        *(unsigned*)&inpA[b * ASTR + 68 + 2 * jp] = *(const unsigned*)&srhrow[b * 64 + 2 * jp];
    }
    if (tid < 128) {
        int b = tid >> 1, i = tid & 1;
        inpA[b * ASTR + i] = (f16)x[(((size_t)b * T_STEPS + tt) * N_NODES + n) * 2 + i];
        inpA[b * ASTR + 66 + i] = SXh[(size_t)n * XCOLS + tt * 128 + b * 2 + i];
    }
    for (int idx = tid; idx < 64 * 14; idx += 256) {
        int b = idx / 14, p = idx % 14;
        *(unsigned*)&inpA[b * ASTR + 132 + 2 * p] = (p == 0) ? 0x00003C00u : 0u;
    }
    __syncthreads();

    int w = tid >> 6, l = tid & 63;
    int lr = l & 15, lg = l >> 4;
    const f16* wbase = WcT + (size_t)(dir * N_NODES + n) * COSTR;

    f32x4 acc[4];
#pragma unroll
    for (int j = 0; j < 4; ++j) acc[j] = (f32x4)(0.f);

#pragma unroll
    for (int kt = 0; kt < 5; ++kt) {
        int k0 = kt * 32 + lg * 8;
        f16x8 af = *(const f16x8*)&inpA[(w * 16 + lr) * ASTR + k0];
        f16x8 bf[4];
#pragma unroll
        for (int j = 0; j < 4; ++j)
            bf[j] = *(const f16x8*)&wbase[(size_t)(j * 16 + lr) * WSTR + k0];
#pragma unroll
        for (int j = 0; j < 4; ++j)
            acc[j] = __builtin_amdgcn_mfma_f32_16x16x32_f16(af, bf[j], acc[j], 0, 0, 0);
    }

    const f16* zrow = Zh + (size_t)(dir * N_NODES + n) * 4096;
    f16* hhrow = Hh + (size_t)n * NCOLS + dir * 4096;
#pragma unroll
    for (int j = 0; j < 4; ++j) {
        int o = j * 16 + lr;
        f32x4 v = acc[j];
#pragma unroll
        for (int q = 0; q < 4; ++q) {
            int b = w * 16 + lg * 4 + q;
            float hc = tanhf(v[q]);
            float zv = (float)zrow[b * 64 + o];
            float hp = (float)hhrow[b * 64 + o];
            float hn = zv * hp + (1.f - zv) * hc;
            if (!last) hhrow[b * 64 + o] = (f16)hn;
            out[(((size_t)b * T_STEPS + t) * N_NODES + n) * 128 + dir * 64 + o] = hn;
        }
    }
}

// ---------------------------------------------------------------------------
extern "C" void kernel_launch(void* const* d_in, const int* in_sizes, int n_in,
                              void* d_out, int out_size, void* d_ws, size_t ws_size,
                              hipStream_t stream) {
    const float* x    = (const float*)d_in[0];
    const float* adj  = (const float*)d_in[1];
    const float* E    = (const float*)d_in[2];
    const float* Wg_f = (const float*)d_in[3];
    const float* bg_f = (const float*)d_in[4];
    const float* Wc_f = (const float*)d_in[5];
    const float* bc_f = (const float*)d_in[6];
    const float* Wg_b = (const float*)d_in[7];
    const float* bg_b = (const float*)d_in[8];
    const float* Wc_b = (const float*)d_in[9];
    const float* bc_b = (const float*)d_in[10];
    float* out = (float*)d_out;

    size_t off = 0;
    auto alloc = [&](size_t bytes) {
        void* p = (char*)d_ws + off;
        off += (bytes + 255) & ~(size_t)255;
        return p;
    };
    f16*   Sh   = (f16*)alloc((size_t)KPAD * KPAD * 2);
    f16*   XTt  = (f16*)alloc((size_t)XCOLS * KPAD * 2);
    f16*   SXh  = (f16*)alloc((size_t)N_NODES * XCOLS * 2);
    f16*   Hh   = (f16*)alloc((size_t)N_NODES * NCOLS * 2);
    f16*   SHh  = (f16*)alloc((size_t)N_NODES * NCOLS * 2);
    f16*   RHh  = (f16*)alloc((size_t)N_NODES * NCOLS * 2);
    f16*   Zh   = (f16*)alloc((size_t)N_NODES * NCOLS * 2);
    f16*   HBt  = (f16*)alloc((size_t)NCOLS * KPAD * 2);
    f16*   RHBt = (f16*)alloc((size_t)NCOLS * KPAD * 2);
    f16*   WgT  = (f16*)alloc((size_t)2 * N_NODES * GOSTR * 2);
    f16*   WcT  = (f16*)alloc((size_t)2 * N_NODES * COSTR * 2);
    // Overlay: Wg_r/Wc_r (2.46 MB, consumed by k_buildW2 before the time loop)
    // live inside RHBt (14.68 MB), first written at t=0's transpose, after
    // buildW2. Keeps workspace within the replay-proven footprint (r6 lesson).
    float* Wg_r = (float*)RHBt;
    float* Wc_r = Wg_r + (size_t)2 * DE * GOSTR;

    hipMemsetAsync(Sh, 0, (size_t)KPAD * KPAD * 2, stream);
    hipMemsetAsync(XTt, 0, (size_t)XCOLS * KPAD * 2, stream);
    hipMemsetAsync(Hh, 0, (size_t)N_NODES * NCOLS * 2, stream);

    k_computeS<<<N_NODES, 256, 0, stream>>>(E, adj, Sh);
    {
        int total = XCOLS * N_NODES;
        k_buildXT<<<(total + 255) / 256, 256, 0, stream>>>(x, XTt);
    }
    {
        int total = 2 * DE * (GOSTR + COSTR);
        k_reorgW<<<(total + 255) / 256, 256, 0, stream>>>(Wg_f, Wg_b, Wc_f, Wc_b,
                                                          bg_f, bg_b, bc_f, bc_b,
                                                          Wg_r, Wc_r);
    }
    k_buildW2<<<dim3(56, 2, 6), 256, 0, stream>>>(E, Wg_r, Wc_r, WgT, WcT);
    k_gemm_f16<<<dim3(XCOLS / 64, 7), 256, 0, stream>>>(Sh, XTt, SXh, XCOLS);

    dim3 gnode(N_NODES, 2);
    dim3 gmain(NCOLS / 64, 7);
    dim3 gtr(NCOLS / 64, KPAD / 64);
    for (int t = 0; t < T_STEPS; ++t) {
        if (t > 0)
            k_gemm_f16<<<gmain, 256, 0, stream>>>(Sh, HBt, SHh, NCOLS);
        k_apply_gate<<<gnode, 256, 0, stream>>>(x, Hh, SXh, SHh, WgT,
                                                Zh, RHh, t, t == 0 ? 1 : 0);
        k_transpose<<<gtr, 256, 0, stream>>>(RHh, RHBt);
        k_gemm_f16<<<gmain, 256, 0, stream>>>(Sh, RHBt, SHh, NCOLS);
        k_apply_cand<<<gnode, 256, 0, stream>>>(x, SXh, SHh, RHh, WcT,
                                                Zh, Hh, out, t,
                                                t == T_STEPS - 1 ? 1 : 0);
        if (t < T_STEPS - 1)
            k_transpose<<<gtr, 256, 0, stream>>>(Hh, HBt);
    }
}